// Round 1
// baseline (247.107 us; speedup 1.0000x reference)
//
#include <hip/hip_runtime.h>
#include <hip/hip_bf16.h>
#include <math.h>

#define BB 8
#define MM 4096
#define DD 512
#define SS 128

#define BM 64
#define BN 64
#define BK 32
#define PAD 4

// ---------------------------------------------------------------------------
// Kernel 1: memory row write + usage decay
// ---------------------------------------------------------------------------
__global__ __launch_bounds__(256) void update_kernel(
    float* __restrict__ memory, const float* __restrict__ usage,
    const float* __restrict__ content, const float* __restrict__ wstr,
    const float* __restrict__ ttab, const float* __restrict__ decay_p,
    const int* __restrict__ widx, float* __restrict__ usage_out) {
  const int b = blockIdx.x;
  int idx = widx[b] % MM; if (idx < 0) idx += MM;
  const float ws = wstr[b];
  const float decay = decay_p[0];
  for (int d = threadIdx.x; d < DD; d += blockDim.x) {
    float cw = content[b * DD + d] + ttab[(size_t)idx * DD + d];
    size_t off = (size_t)b * MM * DD + (size_t)idx * DD + d;
    float old = memory[off];
    memory[off] = old * (1.0f - ws) + cw * ws;
  }
  for (int m = threadIdx.x; m < MM; m += blockDim.x) {
    float u = usage[b * MM + m] * decay;
    if (m == idx) u += ws;
    usage_out[b * MM + m] = u;
  }
}

// ---------------------------------------------------------------------------
// Kernel 2: qp[r][d] = sum_e query[r][e] * W[e][d]   (NN GEMM, R=B*S=1024)
// ---------------------------------------------------------------------------
__global__ __launch_bounds__(256) void gemm_nn_qp(
    const float* __restrict__ A, const float* __restrict__ Bw,
    float* __restrict__ C) {
  __shared__ __align__(16) float As[BK][BM + PAD];
  __shared__ __align__(16) float Bs[BK][BN + PAD];
  const int tid = threadIdx.x;
  const int tx = tid & 15, ty = tid >> 4;
  const int i0 = blockIdx.y * BM;
  const int j0 = blockIdx.x * BN;
  float acc[4][4] = {{0.f}};
  for (int k0 = 0; k0 < DD; k0 += BK) {
#pragma unroll
    for (int r = 0; r < 2; ++r) {
      int ff = tid + r * 256;
      int row = ff >> 3, kq = ff & 7;  // A: 64 rows x 32 k (K-fastest)
      float4 v = *(const float4*)(A + (size_t)(i0 + row) * DD + k0 + kq * 4);
      As[kq * 4 + 0][row] = v.x; As[kq * 4 + 1][row] = v.y;
      As[kq * 4 + 2][row] = v.z; As[kq * 4 + 3][row] = v.w;
      int kr = ff >> 4, jq = ff & 15;  // B: 32 k-rows x 64 cols (N-fastest)
      float4 w = *(const float4*)(Bw + (size_t)(k0 + kr) * DD + j0 + jq * 4);
      *(float4*)&Bs[kr][jq * 4] = w;
    }
    __syncthreads();
#pragma unroll
    for (int k = 0; k < BK; ++k) {
      float4 a = *(const float4*)&As[k][ty * 4];
      float4 bb = *(const float4*)&Bs[k][tx * 4];
      float av[4] = {a.x, a.y, a.z, a.w};
      float bv[4] = {bb.x, bb.y, bb.z, bb.w};
#pragma unroll
      for (int i = 0; i < 4; ++i)
#pragma unroll
        for (int j = 0; j < 4; ++j) acc[i][j] += av[i] * bv[j];
    }
    __syncthreads();
  }
#pragma unroll
  for (int i = 0; i < 4; ++i) {
    float4 o = make_float4(acc[i][0], acc[i][1], acc[i][2], acc[i][3]);
    *(float4*)(C + (size_t)(i0 + ty * 4 + i) * DD + j0 + tx * 4) = o;
  }
}

// ---------------------------------------------------------------------------
// Kernel 3: scores[b][s][m] = (1/sqrt(D)) * sum_k qp[b][s][k] * mem[b][m][k]
// NT GEMM per batch (both operands K-fastest).
// ---------------------------------------------------------------------------
__global__ __launch_bounds__(256) void gemm_nt_scores(
    const float* __restrict__ qp, const float* __restrict__ mem,
    float* __restrict__ sc_out) {
  __shared__ __align__(16) float As[BK][BM + PAD];
  __shared__ __align__(16) float Bs[BK][BN + PAD];
  const int tid = threadIdx.x;
  const int tx = tid & 15, ty = tid >> 4;
  const int b = blockIdx.z;
  const int i0 = blockIdx.y * BM;  // over S
  const int j0 = blockIdx.x * BN;  // over M
  const float* A = qp + (size_t)b * SS * DD;
  const float* Bm = mem + (size_t)b * MM * DD;
  float* C = sc_out + (size_t)b * SS * MM;
  float acc[4][4] = {{0.f}};
  for (int k0 = 0; k0 < DD; k0 += BK) {
#pragma unroll
    for (int r = 0; r < 2; ++r) {
      int ff = tid + r * 256;
      int row = ff >> 3, kq = ff & 7;
      float4 v = *(const float4*)(A + (size_t)(i0 + row) * DD + k0 + kq * 4);
      As[kq * 4 + 0][row] = v.x; As[kq * 4 + 1][row] = v.y;
      As[kq * 4 + 2][row] = v.z; As[kq * 4 + 3][row] = v.w;
      float4 w = *(const float4*)(Bm + (size_t)(j0 + row) * DD + k0 + kq * 4);
      Bs[kq * 4 + 0][row] = w.x; Bs[kq * 4 + 1][row] = w.y;
      Bs[kq * 4 + 2][row] = w.z; Bs[kq * 4 + 3][row] = w.w;
    }
    __syncthreads();
#pragma unroll
    for (int k = 0; k < BK; ++k) {
      float4 a = *(const float4*)&As[k][ty * 4];
      float4 bb = *(const float4*)&Bs[k][tx * 4];
      float av[4] = {a.x, a.y, a.z, a.w};
      float bv[4] = {bb.x, bb.y, bb.z, bb.w};
#pragma unroll
      for (int i = 0; i < 4; ++i)
#pragma unroll
        for (int j = 0; j < 4; ++j) acc[i][j] += av[i] * bv[j];
    }
    __syncthreads();
  }
  const float scl = 0.04419417382415922f;  // 1/sqrt(512)
#pragma unroll
  for (int i = 0; i < 4; ++i) {
    float4 o = make_float4(acc[i][0] * scl, acc[i][1] * scl,
                           acc[i][2] * scl, acc[i][3] * scl);
    *(float4*)(C + (size_t)(i0 + ty * 4 + i) * MM + j0 + tx * 4) = o;
  }
}

// ---------------------------------------------------------------------------
// Kernel 4: per (b,s) row — mask, exact top-k threshold (radix select on
// order-preserving float bits), softmax, dense attn write, retrieved gather.
// ---------------------------------------------------------------------------
__device__ __forceinline__ unsigned fkey(float f) {
  unsigned u = __float_as_uint(f);
  return (u & 0x80000000u) ? ~u : (u | 0x80000000u);
}
__device__ __forceinline__ float finv(unsigned u) {
  unsigned b = (u & 0x80000000u) ? (u & 0x7fffffffu) : ~u;
  return __uint_as_float(b);
}

__global__ __launch_bounds__(256) void select_kernel(
    const float* __restrict__ scores, const int* __restrict__ vmask,
    const int* __restrict__ widx, const int* __restrict__ topk,
    const float* __restrict__ memory, float* __restrict__ retrieved,
    float* __restrict__ attn) {
  __shared__ float sc[MM];        // 16 KB: scores row, later unnormalized probs
  __shared__ int kept[MM];        // 16 KB: surviving indices
  __shared__ unsigned hist[257];
  __shared__ float red[256];
  __shared__ unsigned sh_pref;
  __shared__ int sh_k, sh_nkept;
  __shared__ float sh_maxv, sh_zinv;

  const int tid = threadIdx.x;
  const int s = blockIdx.x, b = blockIdx.y;
  int wi = widx[b] % MM; if (wi < 0) wi += MM;
  const float* srow = scores + ((size_t)b * SS + s) * MM;
  const int* vrow = vmask + (size_t)b * MM;

  // load + mask + row max
  float lmax = -INFINITY;
  for (int m = tid; m < MM; m += 256) {
    float v = srow[m];
    bool ok = (vrow[m] != 0) || (m == wi);
    v = ok ? v : -INFINITY;
    sc[m] = v;
    lmax = fmaxf(lmax, v);
  }
  red[tid] = lmax;
  __syncthreads();
  for (int off = 128; off > 0; off >>= 1) {
    if (tid < off) red[tid] = fmaxf(red[tid], red[tid + off]);
    __syncthreads();
  }
  if (tid == 0) { sh_maxv = red[0]; sh_pref = 0u; sh_k = topk[0]; }
  __syncthreads();
  const float maxv = sh_maxv;

  // 4-pass radix select: exact k-th largest value (counting duplicates)
  for (int pass = 0; pass < 4; ++pass) {
    const int shift = 24 - pass * 8;
    hist[tid] = 0u;
    if (tid == 0) hist[256] = 0u;
    __syncthreads();
    const unsigned pref = sh_pref;
    const unsigned hmask = (pass == 0) ? 0u : (0xFFFFFFFFu << (shift + 8));
    for (int m = tid; m < MM; m += 256) {
      unsigned u = fkey(sc[m]);
      if ((u & hmask) == pref) atomicAdd(&hist[(u >> shift) & 0xFFu], 1u);
    }
    __syncthreads();
    // inclusive suffix sum over 256 bins
    for (int off = 1; off < 256; off <<= 1) {
      unsigned v = (tid + off < 256) ? hist[tid + off] : 0u;
      __syncthreads();
      hist[tid] += v;
      __syncthreads();
    }
    const int k = sh_k;
    const unsigned ge = hist[tid];
    const unsigned geN = hist[tid + 1];
    if (ge >= (unsigned)k && geN < (unsigned)k) {
      sh_pref = pref | ((unsigned)tid << shift);
      sh_k = k - (int)geN;
    }
    __syncthreads();
  }
  const float thr = finv(sh_pref);

  // unnormalized probs + Z  (exp(-inf)=0 handles invalid rows of any thr)
  float lz = 0.f;
  for (int m = tid; m < MM; m += 256) {
    float v = sc[m];
    float p = (v >= thr) ? __expf(v - maxv) : 0.f;
    sc[m] = p;
    lz += p;
  }
  red[tid] = lz;
  __syncthreads();
  for (int off = 128; off > 0; off >>= 1) {
    if (tid < off) red[tid] += red[tid + off];
    __syncthreads();
  }
  if (tid == 0) { sh_zinv = 1.0f / red[0]; sh_nkept = 0; }
  __syncthreads();
  const float zinv = sh_zinv;

  // dense attn write + kept list
  float* arow = attn + ((size_t)b * SS + s) * MM;
  for (int m = tid; m < MM; m += 256) {
    float p = sc[m];
    arow[m] = p * zinv;
    if (p > 0.f) {
      int pos = atomicAdd(&sh_nkept, 1);
      kept[pos] = m;
    }
  }
  __syncthreads();
  const int nk = sh_nkept;

  // retrieved[b][s][d] = sum over kept of attn * memory
  float a0 = 0.f, a1 = 0.f;
  const float* mb = memory + (size_t)b * MM * DD;
  for (int i = 0; i < nk; ++i) {
    int m = kept[i];
    float p = sc[m];
    const float* mr = mb + (size_t)m * DD;
    a0 += p * mr[tid];
    a1 += p * mr[tid + 256];
  }
  float* rrow = retrieved + ((size_t)b * SS + s) * DD;
  rrow[tid] = a0 * zinv;
  rrow[tid + 256] = a1 * zinv;
}

// ---------------------------------------------------------------------------
extern "C" void kernel_launch(void* const* d_in, const int* in_sizes, int n_in,
                              void* d_out, int out_size, void* d_ws,
                              size_t ws_size, hipStream_t stream) {
  float* memory = (float*)d_in[0];              // [B][M][D] (updated in place)
  const float* usage = (const float*)d_in[1];   // [B][M]
  const float* content = (const float*)d_in[2]; // [B][D]
  const float* wstr = (const float*)d_in[3];    // [B][1]
  const float* query = (const float*)d_in[4];   // [B][S][D]
  const float* W = (const float*)d_in[5];       // [D][D] (e,d)
  const float* ttab = (const float*)d_in[6];    // [M][D]
  const float* decay = (const float*)d_in[7];   // [1]
  const int* vmask = (const int*)d_in[8];       // [B][M]
  const int* widx = (const int*)d_in[9];        // [B]
  const int* topk = (const int*)d_in[10];       // [1]

  float* out = (float*)d_out;
  float* retrieved = out;                              // B*S*D
  float* attn = out + (size_t)BB * SS * DD;            // B*S*M
  float* usage_out = attn + (size_t)BB * SS * MM;      // B*M

  float* scores = (float*)d_ws;                        // B*S*M floats (16 MB)
  float* qp = scores + (size_t)BB * SS * MM;           // B*S*D floats (2 MB)

  update_kernel<<<BB, 256, 0, stream>>>(memory, usage, content, wstr, ttab,
                                        decay, widx, usage_out);
  gemm_nn_qp<<<dim3(DD / BN, (BB * SS) / BM), 256, 0, stream>>>(query, W, qp);
  gemm_nt_scores<<<dim3(MM / BN, SS / BM, BB), 256, 0, stream>>>(qp, memory,
                                                                 scores);
  select_kernel<<<dim3(SS, BB), 256, 0, stream>>>(scores, vmask, widx, topk,
                                                  memory, retrieved, attn);
}

// Round 3
// 205.084 us; speedup vs baseline: 1.2049x; 1.2049x over previous
//
#include <hip/hip_runtime.h>
#include <hip/hip_bf16.h>
#include <math.h>

#define BB 8
#define MM 4096
#define DD 512
#define SS 128

typedef short s16x8 __attribute__((ext_vector_type(8)));
typedef float f32x4 __attribute__((ext_vector_type(4)));

__device__ __forceinline__ unsigned short f2bf(float x) {
  unsigned u = __float_as_uint(x);
  unsigned r = u + 0x7fffu + ((u >> 16) & 1u);
  return (unsigned short)(r >> 16);
}
__device__ __forceinline__ float bf2f(unsigned short h) {
  return __uint_as_float(((unsigned)h) << 16);
}
// 3-way split: x ~= s1 + s2 + s3, residual <= 2^-26 |x|
__device__ __forceinline__ void split3(float x, unsigned short& s1,
                                       unsigned short& s2, unsigned short& s3) {
  s1 = f2bf(x);
  float r1 = x - bf2f(s1);
  s2 = f2bf(r1);
  float r2 = r1 - bf2f(s2);
  s3 = f2bf(r2);
}

// ---------------------------------------------------------------------------
// Kernel 1: memory row write + usage decay
// ---------------------------------------------------------------------------
__global__ __launch_bounds__(256) void update_kernel(
    float* __restrict__ memory, const float* __restrict__ usage,
    const float* __restrict__ content, const float* __restrict__ wstr,
    const float* __restrict__ ttab, const float* __restrict__ decay_p,
    const int* __restrict__ widx, float* __restrict__ usage_out) {
  const int b = blockIdx.x;
  int idx = widx[b] % MM; if (idx < 0) idx += MM;
  const float ws = wstr[b];
  const float decay = decay_p[0];
  for (int d = threadIdx.x; d < DD; d += blockDim.x) {
    float cw = content[b * DD + d] + ttab[(size_t)idx * DD + d];
    size_t off = (size_t)b * MM * DD + (size_t)idx * DD + d;
    float old = memory[off];
    memory[off] = old * (1.0f - ws) + cw * ws;
  }
  for (int m = threadIdx.x; m < MM; m += blockDim.x) {
    float u = usage[b * MM + m] * decay;
    if (m == idx) u += ws;
    usage_out[b * MM + m] = u;
  }
}

// ---------------------------------------------------------------------------
// Kernel 2: qp = query @ W (fp32 VALU GEMM); epilogue emits 3-way bf16 split.
// ---------------------------------------------------------------------------
#define BMq 64
#define BNq 64
#define BKq 32
#define PADq 4

__global__ __launch_bounds__(256) void gemm_nn_qp(
    const float* __restrict__ A, const float* __restrict__ Bw,
    unsigned short* __restrict__ q1, unsigned short* __restrict__ q2,
    unsigned short* __restrict__ q3) {
  __shared__ __align__(16) float As[BKq][BMq + PADq];
  __shared__ __align__(16) float Bs[BKq][BNq + PADq];
  const int tid = threadIdx.x;
  const int tx = tid & 15, ty = tid >> 4;
  const int i0 = blockIdx.y * BMq;
  const int j0 = blockIdx.x * BNq;
  float acc[4][4] = {{0.f}};
  for (int k0 = 0; k0 < DD; k0 += BKq) {
#pragma unroll
    for (int r = 0; r < 2; ++r) {
      int ff = tid + r * 256;
      int row = ff >> 3, kq = ff & 7;
      float4 v = *(const float4*)(A + (size_t)(i0 + row) * DD + k0 + kq * 4);
      As[kq * 4 + 0][row] = v.x; As[kq * 4 + 1][row] = v.y;
      As[kq * 4 + 2][row] = v.z; As[kq * 4 + 3][row] = v.w;
      int kr = ff >> 4, jq = ff & 15;
      float4 w = *(const float4*)(Bw + (size_t)(k0 + kr) * DD + j0 + jq * 4);
      *(float4*)&Bs[kr][jq * 4] = w;
    }
    __syncthreads();
#pragma unroll
    for (int k = 0; k < BKq; ++k) {
      float4 a = *(const float4*)&As[k][ty * 4];
      float4 bb = *(const float4*)&Bs[k][tx * 4];
      float av[4] = {a.x, a.y, a.z, a.w};
      float bv[4] = {bb.x, bb.y, bb.z, bb.w};
#pragma unroll
      for (int i = 0; i < 4; ++i)
#pragma unroll
        for (int j = 0; j < 4; ++j) acc[i][j] += av[i] * bv[j];
    }
    __syncthreads();
  }
#pragma unroll
  for (int i = 0; i < 4; ++i) {
    int row = i0 + ty * 4 + i;
    ushort4 v1, v2, v3;
    split3(acc[i][0], v1.x, v2.x, v3.x);
    split3(acc[i][1], v1.y, v2.y, v3.y);
    split3(acc[i][2], v1.z, v2.z, v3.z);
    split3(acc[i][3], v1.w, v2.w, v3.w);
    *(ushort4*)(q1 + (size_t)row * DD + j0 + tx * 4) = v1;
    *(ushort4*)(q2 + (size_t)row * DD + j0 + tx * 4) = v2;
    *(ushort4*)(q3 + (size_t)row * DD + j0 + tx * 4) = v3;
  }
}

// ---------------------------------------------------------------------------
// Kernel 3: scores via 3-way-split bf16 MFMA (6 terms -> error below fp32
// product rounding). Tile 128(S) x 64(M) x 32(K). memory fp32 -> 3x bf16
// fused in staging. Two accumulators: accA = q1*m1 (O(1) terms), accB = the
// five O(2^-8)/O(2^-16) correction terms.
// ---------------------------------------------------------------------------
#define LSTR 40  // LDS row stride in bf16 elems (32 + 8 pad)

__global__ __launch_bounds__(256, 2) void gemm_scores_mfma(
    const unsigned short* __restrict__ q1_g,
    const unsigned short* __restrict__ q2_g,
    const unsigned short* __restrict__ q3_g,
    const float* __restrict__ mem, float* __restrict__ sc_out) {
  __shared__ __align__(16) unsigned short q1_s[128 * LSTR];
  __shared__ __align__(16) unsigned short q2_s[128 * LSTR];
  __shared__ __align__(16) unsigned short q3_s[128 * LSTR];
  __shared__ __align__(16) unsigned short m1_s[64 * LSTR];
  __shared__ __align__(16) unsigned short m2_s[64 * LSTR];
  __shared__ __align__(16) unsigned short m3_s[64 * LSTR];
  const int tid = threadIdx.x;
  const int b = blockIdx.x & 7;                 // XCD-pinned batch
  const int j0 = (blockIdx.x >> 3) * 64;
  const int wv = tid >> 6, lane = tid & 63;
  const int quad = lane >> 4, r = lane & 15;

  const int qrow0 = tid >> 2, qc0 = tid & 3;
  const int qrow1 = (tid + 256) >> 2, qc1 = tid & 3;
  const unsigned short* q1b = q1_g + (size_t)b * SS * DD;
  const unsigned short* q2b = q2_g + (size_t)b * SS * DD;
  const unsigned short* q3b = q3_g + (size_t)b * SS * DD;
  const int mrow0 = tid >> 3, mk0 = tid & 7;
  const int mrow1 = (tid + 256) >> 3, mk1 = tid & 7;
  const float* mbase = mem + ((size_t)b * MM + j0) * DD;

  f32x4 accA[2][4], accB[2][4];
#pragma unroll
  for (int i = 0; i < 2; ++i)
#pragma unroll
    for (int j = 0; j < 4; ++j)
#pragma unroll
      for (int c = 0; c < 4; ++c) { accA[i][j][c] = 0.f; accB[i][j][c] = 0.f; }

  uint4 q1_r0, q1_r1, q2_r0, q2_r1, q3_r0, q3_r1;
  float4 m_r0, m_r1;

  q1_r0 = *(const uint4*)(q1b + (size_t)qrow0 * DD + qc0 * 8);
  q1_r1 = *(const uint4*)(q1b + (size_t)qrow1 * DD + qc1 * 8);
  q2_r0 = *(const uint4*)(q2b + (size_t)qrow0 * DD + qc0 * 8);
  q2_r1 = *(const uint4*)(q2b + (size_t)qrow1 * DD + qc1 * 8);
  q3_r0 = *(const uint4*)(q3b + (size_t)qrow0 * DD + qc0 * 8);
  q3_r1 = *(const uint4*)(q3b + (size_t)qrow1 * DD + qc1 * 8);
  m_r0 = *(const float4*)(mbase + (size_t)mrow0 * DD + mk0 * 4);
  m_r1 = *(const float4*)(mbase + (size_t)mrow1 * DD + mk1 * 4);

  for (int ks = 0; ks < 16; ++ks) {
    if (ks) __syncthreads();
    *(uint4*)&q1_s[qrow0 * LSTR + qc0 * 8] = q1_r0;
    *(uint4*)&q1_s[qrow1 * LSTR + qc1 * 8] = q1_r1;
    *(uint4*)&q2_s[qrow0 * LSTR + qc0 * 8] = q2_r0;
    *(uint4*)&q2_s[qrow1 * LSTR + qc1 * 8] = q2_r1;
    *(uint4*)&q3_s[qrow0 * LSTR + qc0 * 8] = q3_r0;
    *(uint4*)&q3_s[qrow1 * LSTR + qc1 * 8] = q3_r1;
    {
      ushort4 v1, v2, v3;
      split3(m_r0.x, v1.x, v2.x, v3.x);
      split3(m_r0.y, v1.y, v2.y, v3.y);
      split3(m_r0.z, v1.z, v2.z, v3.z);
      split3(m_r0.w, v1.w, v2.w, v3.w);
      *(ushort4*)&m1_s[mrow0 * LSTR + mk0 * 4] = v1;
      *(ushort4*)&m2_s[mrow0 * LSTR + mk0 * 4] = v2;
      *(ushort4*)&m3_s[mrow0 * LSTR + mk0 * 4] = v3;
      split3(m_r1.x, v1.x, v2.x, v3.x);
      split3(m_r1.y, v1.y, v2.y, v3.y);
      split3(m_r1.z, v1.z, v2.z, v3.z);
      split3(m_r1.w, v1.w, v2.w, v3.w);
      *(ushort4*)&m1_s[mrow1 * LSTR + mk1 * 4] = v1;
      *(ushort4*)&m2_s[mrow1 * LSTR + mk1 * 4] = v2;
      *(ushort4*)&m3_s[mrow1 * LSTR + mk1 * 4] = v3;
    }
    __syncthreads();
    if (ks < 15) {
      int k0 = (ks + 1) * 32;
      q1_r0 = *(const uint4*)(q1b + (size_t)qrow0 * DD + k0 + qc0 * 8);
      q1_r1 = *(const uint4*)(q1b + (size_t)qrow1 * DD + k0 + qc1 * 8);
      q2_r0 = *(const uint4*)(q2b + (size_t)qrow0 * DD + k0 + qc0 * 8);
      q2_r1 = *(const uint4*)(q2b + (size_t)qrow1 * DD + k0 + qc1 * 8);
      q3_r0 = *(const uint4*)(q3b + (size_t)qrow0 * DD + k0 + qc0 * 8);
      q3_r1 = *(const uint4*)(q3b + (size_t)qrow1 * DD + k0 + qc1 * 8);
      m_r0 = *(const float4*)(mbase + (size_t)mrow0 * DD + k0 + mk0 * 4);
      m_r1 = *(const float4*)(mbase + (size_t)mrow1 * DD + k0 + mk1 * 4);
    }
    s16x8 a1[2], a2[2], a3[2];
#pragma unroll
    for (int st = 0; st < 2; ++st) {
      int arow = wv * 32 + st * 16 + r;
      a1[st] = *(const s16x8*)&q1_s[arow * LSTR + quad * 8];
      a2[st] = *(const s16x8*)&q2_s[arow * LSTR + quad * 8];
      a3[st] = *(const s16x8*)&q3_s[arow * LSTR + quad * 8];
    }
#pragma unroll
    for (int jt = 0; jt < 4; ++jt) {
      int brow = jt * 16 + r;
      s16x8 b1 = *(const s16x8*)&m1_s[brow * LSTR + quad * 8];
      s16x8 b2 = *(const s16x8*)&m2_s[brow * LSTR + quad * 8];
      s16x8 b3 = *(const s16x8*)&m3_s[brow * LSTR + quad * 8];
#pragma unroll
      for (int st = 0; st < 2; ++st) {
        accB[st][jt] = __builtin_amdgcn_mfma_f32_16x16x32_bf16(a1[st], b3, accB[st][jt], 0, 0, 0);
        accB[st][jt] = __builtin_amdgcn_mfma_f32_16x16x32_bf16(a3[st], b1, accB[st][jt], 0, 0, 0);
        accB[st][jt] = __builtin_amdgcn_mfma_f32_16x16x32_bf16(a2[st], b2, accB[st][jt], 0, 0, 0);
        accB[st][jt] = __builtin_amdgcn_mfma_f32_16x16x32_bf16(a1[st], b2, accB[st][jt], 0, 0, 0);
        accB[st][jt] = __builtin_amdgcn_mfma_f32_16x16x32_bf16(a2[st], b1, accB[st][jt], 0, 0, 0);
        accA[st][jt] = __builtin_amdgcn_mfma_f32_16x16x32_bf16(a1[st], b1, accA[st][jt], 0, 0, 0);
      }
    }
  }
  // epilogue: C/D layout col=lane&15, row=quad*4+reg
  const float scl = 0.04419417382415922f;  // 1/sqrt(512)
  float* C = sc_out + (size_t)b * SS * MM;
#pragma unroll
  for (int st = 0; st < 2; ++st)
#pragma unroll
    for (int jt = 0; jt < 4; ++jt)
#pragma unroll
      for (int reg = 0; reg < 4; ++reg) {
        int srow = wv * 32 + st * 16 + quad * 4 + reg;
        int scol = j0 + jt * 16 + r;
        C[(size_t)srow * MM + scol] = (accA[st][jt][reg] + accB[st][jt][reg]) * scl;
      }
}

// ---------------------------------------------------------------------------
// Kernel 4: per (b,s) row — mask, exact top-k threshold (radix select),
// softmax, dense attn write, retrieved gather.
// ---------------------------------------------------------------------------
__device__ __forceinline__ unsigned fkey(float f) {
  unsigned u = __float_as_uint(f);
  return (u & 0x80000000u) ? ~u : (u | 0x80000000u);
}
__device__ __forceinline__ float finv(unsigned u) {
  unsigned b = (u & 0x80000000u) ? (u & 0x7fffffffu) : ~u;
  return __uint_as_float(b);
}

__global__ __launch_bounds__(256) void select_kernel(
    const float* __restrict__ scores, const int* __restrict__ vmask,
    const int* __restrict__ widx, const int* __restrict__ topk,
    const float* __restrict__ memory, float* __restrict__ retrieved,
    float* __restrict__ attn) {
  __shared__ float sc[MM];
  __shared__ int kept[MM];
  __shared__ unsigned histw[4 * 256];
  __shared__ float red[256];
  __shared__ unsigned sh_pref;
  __shared__ int sh_k, sh_nkept;
  __shared__ float sh_zinv;

  const int tid = threadIdx.x;
  const int s = blockIdx.x, b = blockIdx.y;
  int wi = widx[b] % MM; if (wi < 0) wi += MM;
  const float4* srow4 = (const float4*)(scores + ((size_t)b * SS + s) * MM);
  const int4* vrow4 = (const int4*)(vmask + (size_t)b * MM);
  unsigned* hw = histw + (tid >> 6) * 256;

  if (tid == 0) { sh_pref = 0u; sh_nkept = 0; sh_k = topk[0]; }
  for (int i = tid; i < 1024; i += 256) histw[i] = 0u;
  __syncthreads();

  float lmax = -INFINITY;
  for (int m4 = tid; m4 < MM / 4; m4 += 256) {
    float4 v = srow4[m4];
    int4 mk = vrow4[m4];
    int mb = m4 * 4;
    if (!(mk.x || mb + 0 == wi)) v.x = -INFINITY;
    if (!(mk.y || mb + 1 == wi)) v.y = -INFINITY;
    if (!(mk.z || mb + 2 == wi)) v.z = -INFINITY;
    if (!(mk.w || mb + 3 == wi)) v.w = -INFINITY;
    ((float4*)sc)[m4] = v;
    lmax = fmaxf(lmax, fmaxf(fmaxf(v.x, v.y), fmaxf(v.z, v.w)));
    atomicAdd(&hw[fkey(v.x) >> 24], 1u);
    atomicAdd(&hw[fkey(v.y) >> 24], 1u);
    atomicAdd(&hw[fkey(v.z) >> 24], 1u);
    atomicAdd(&hw[fkey(v.w) >> 24], 1u);
  }
  red[tid] = lmax;
  __syncthreads();
#pragma unroll
  for (int off = 128; off > 0; off >>= 1) {
    if (tid < off) red[tid] = fmaxf(red[tid], red[tid + off]);
    __syncthreads();
  }
  const float maxv = red[0];

  for (int pass = 0; pass < 4; ++pass) {
    const int shift = 24 - pass * 8;
    if (pass > 0) {
      const unsigned pref = sh_pref;
      const unsigned hmask = 0xFFFFFFFFu << (shift + 8);
      for (int i = tid; i < 1024; i += 256) histw[i] = 0u;
      __syncthreads();
      for (int m = tid; m < MM; m += 256) {
        unsigned u = fkey(sc[m]);
        if ((u & hmask) == pref) atomicAdd(&hw[(u >> shift) & 0xFFu], 1u);
      }
      __syncthreads();
    }
    if (tid < 64) {
      const int l = tid;
      unsigned h0 = histw[l * 4 + 0] + histw[256 + l * 4 + 0] + histw[512 + l * 4 + 0] + histw[768 + l * 4 + 0];
      unsigned h1 = histw[l * 4 + 1] + histw[256 + l * 4 + 1] + histw[512 + l * 4 + 1] + histw[768 + l * 4 + 1];
      unsigned h2 = histw[l * 4 + 2] + histw[256 + l * 4 + 2] + histw[512 + l * 4 + 2] + histw[768 + l * 4 + 2];
      unsigned h3 = histw[l * 4 + 3] + histw[256 + l * 4 + 3] + histw[512 + l * 4 + 3] + histw[768 + l * 4 + 3];
      unsigned lsum = h0 + h1 + h2 + h3;
      unsigned g = lsum;
#pragma unroll
      for (int off = 1; off < 64; off <<= 1) {
        unsigned t = __shfl_down(g, off, 64);
        if (l + off < 64) g += t;
      }
      unsigned above = g - lsum;
      unsigned suf3 = h3 + above;
      unsigned suf2 = h2 + suf3;
      unsigned suf1 = h1 + suf2;
      unsigned suf0 = h0 + suf1;
      const unsigned kk = (unsigned)sh_k;
      const unsigned prefc = sh_pref;
      unsigned ge, geN;
      ge = suf0; geN = suf1;
      if (ge >= kk && geN < kk) { sh_pref = prefc | ((unsigned)(4 * l + 0) << shift); sh_k = (int)(kk - geN); }
      ge = suf1; geN = suf2;
      if (ge >= kk && geN < kk) { sh_pref = prefc | ((unsigned)(4 * l + 1) << shift); sh_k = (int)(kk - geN); }
      ge = suf2; geN = suf3;
      if (ge >= kk && geN < kk) { sh_pref = prefc | ((unsigned)(4 * l + 2) << shift); sh_k = (int)(kk - geN); }
      ge = suf3; geN = above;
      if (ge >= kk && geN < kk) { sh_pref = prefc | ((unsigned)(4 * l + 3) << shift); sh_k = (int)(kk - geN); }
    }
    __syncthreads();
  }
  const float thr = finv(sh_pref);

  float lz = 0.f;
  for (int m4 = tid; m4 < MM / 4; m4 += 256) {
    float4 v = ((float4*)sc)[m4];
    v.x = (v.x >= thr) ? __expf(v.x - maxv) : 0.f;
    v.y = (v.y >= thr) ? __expf(v.y - maxv) : 0.f;
    v.z = (v.z >= thr) ? __expf(v.z - maxv) : 0.f;
    v.w = (v.w >= thr) ? __expf(v.w - maxv) : 0.f;
    ((float4*)sc)[m4] = v;
    lz += v.x + v.y + v.z + v.w;
  }
  red[tid] = lz;
  __syncthreads();
#pragma unroll
  for (int off = 128; off > 0; off >>= 1) {
    if (tid < off) red[tid] += red[tid + off];
    __syncthreads();
  }
  if (tid == 0) sh_zinv = 1.0f / red[0];
  __syncthreads();
  const float zinv = sh_zinv;

  float4* arow4 = (float4*)(attn + ((size_t)b * SS + s) * MM);
  for (int m4 = tid; m4 < MM / 4; m4 += 256) {
    float4 p = ((float4*)sc)[m4];
    float4 o = make_float4(p.x * zinv, p.y * zinv, p.z * zinv, p.w * zinv);
    arow4[m4] = o;
    int mb = m4 * 4;
    if (p.x > 0.f) kept[atomicAdd(&sh_nkept, 1)] = mb + 0;
    if (p.y > 0.f) kept[atomicAdd(&sh_nkept, 1)] = mb + 1;
    if (p.z > 0.f) kept[atomicAdd(&sh_nkept, 1)] = mb + 2;
    if (p.w > 0.f) kept[atomicAdd(&sh_nkept, 1)] = mb + 3;
  }
  __syncthreads();
  const int nk = sh_nkept;

  float a0 = 0.f, a1 = 0.f;
  const float* mb_ = memory + (size_t)b * MM * DD;
  int i = 0;
  for (; i + 4 <= nk; i += 4) {
    int m0 = kept[i], m1 = kept[i + 1], m2 = kept[i + 2], m3 = kept[i + 3];
    float p0 = sc[m0], p1 = sc[m1], p2 = sc[m2], p3 = sc[m3];
    const float* r0 = mb_ + (size_t)m0 * DD;
    const float* r1 = mb_ + (size_t)m1 * DD;
    const float* r2 = mb_ + (size_t)m2 * DD;
    const float* r3 = mb_ + (size_t)m3 * DD;
    float v0a = r0[tid], v0b = r0[tid + 256];
    float v1a = r1[tid], v1b = r1[tid + 256];
    float v2a = r2[tid], v2b = r2[tid + 256];
    float v3a = r3[tid], v3b = r3[tid + 256];
    a0 += p0 * v0a + p1 * v1a + p2 * v2a + p3 * v3a;
    a1 += p0 * v0b + p1 * v1b + p2 * v2b + p3 * v3b;
  }
  for (; i < nk; ++i) {
    int m = kept[i];
    float p = sc[m];
    const float* mr = mb_ + (size_t)m * DD;
    a0 += p * mr[tid];
    a1 += p * mr[tid + 256];
  }
  float* rrow = retrieved + ((size_t)b * SS + s) * DD;
  rrow[tid] = a0 * zinv;
  rrow[tid + 256] = a1 * zinv;
}

// ---------------------------------------------------------------------------
extern "C" void kernel_launch(void* const* d_in, const int* in_sizes, int n_in,
                              void* d_out, int out_size, void* d_ws,
                              size_t ws_size, hipStream_t stream) {
  float* memory = (float*)d_in[0];
  const float* usage = (const float*)d_in[1];
  const float* content = (const float*)d_in[2];
  const float* wstr = (const float*)d_in[3];
  const float* query = (const float*)d_in[4];
  const float* W = (const float*)d_in[5];
  const float* ttab = (const float*)d_in[6];
  const float* decay = (const float*)d_in[7];
  const int* vmask = (const int*)d_in[8];
  const int* widx = (const int*)d_in[9];
  const int* topk = (const int*)d_in[10];

  float* out = (float*)d_out;
  float* retrieved = out;                              // B*S*D floats
  float* attn = out + (size_t)BB * SS * DD;            // B*S*M floats
  float* usage_out = attn + (size_t)BB * SS * MM;      // B*M floats

  const size_t qsz = (size_t)BB * SS * DD;             // elems per q array
  float* scores = (float*)d_ws;                        // 16 MB
  unsigned short* q1 = (unsigned short*)(scores + (size_t)BB * SS * MM);
  unsigned short* q2 = q1 + qsz;
  unsigned short* q3;
  size_t need3 = (size_t)BB * SS * MM * 4 + 3 * qsz * 2;
  if (ws_size >= need3) {
    q3 = q2 + qsz;  // fits in workspace
  } else {
    // carve the tail of the attn output region (select overwrites it later;
    // same-stream ordering makes this safe)
    q3 = (unsigned short*)(attn + (size_t)BB * SS * MM) - qsz;
  }

  update_kernel<<<BB, 256, 0, stream>>>(memory, usage, content, wstr, ttab,
                                        decay, widx, usage_out);
  gemm_nn_qp<<<dim3(DD / BNq, (BB * SS) / BMq), 256, 0, stream>>>(query, W, q1,
                                                                  q2, q3);
  gemm_scores_mfma<<<dim3((MM / 64) * BB), 256, 0, stream>>>(q1, q2, q3,
                                                             memory, scores);
  select_kernel<<<dim3(SS, BB), 256, 0, stream>>>(scores, vmask, widx, topk,
                                                  memory, retrieved, attn);
}

// Round 4
// 203.395 us; speedup vs baseline: 1.2149x; 1.0083x over previous
//
#include <hip/hip_runtime.h>
#include <hip/hip_bf16.h>
#include <math.h>

#define BB 8
#define MM 4096
#define DD 512
#define SS 128

typedef short s16x8 __attribute__((ext_vector_type(8)));
typedef float f32x4 __attribute__((ext_vector_type(4)));

__device__ __forceinline__ unsigned short f2bf(float x) {
  unsigned u = __float_as_uint(x);
  unsigned r = u + 0x7fffu + ((u >> 16) & 1u);
  return (unsigned short)(r >> 16);
}
__device__ __forceinline__ float bf2f(unsigned short h) {
  return __uint_as_float(((unsigned)h) << 16);
}
// 3-way split: x ~= s1 + s2 + s3, residual <= 2^-26 |x|
__device__ __forceinline__ void split3(float x, unsigned short& s1,
                                       unsigned short& s2, unsigned short& s3) {
  s1 = f2bf(x);
  float r1 = x - bf2f(s1);
  s2 = f2bf(r1);
  float r2 = r1 - bf2f(s2);
  s3 = f2bf(r2);
}

// ---------------------------------------------------------------------------
// Kernel 1: memory row write + usage decay
// ---------------------------------------------------------------------------
__global__ __launch_bounds__(256) void update_kernel(
    float* __restrict__ memory, const float* __restrict__ usage,
    const float* __restrict__ content, const float* __restrict__ wstr,
    const float* __restrict__ ttab, const float* __restrict__ decay_p,
    const int* __restrict__ widx, float* __restrict__ usage_out) {
  const int b = blockIdx.x;
  int idx = widx[b] % MM; if (idx < 0) idx += MM;
  const float ws = wstr[b];
  const float decay = decay_p[0];
  for (int d = threadIdx.x; d < DD; d += blockDim.x) {
    float cw = content[b * DD + d] + ttab[(size_t)idx * DD + d];
    size_t off = (size_t)b * MM * DD + (size_t)idx * DD + d;
    float old = memory[off];
    memory[off] = old * (1.0f - ws) + cw * ws;
  }
  for (int m = threadIdx.x; m < MM; m += blockDim.x) {
    float u = usage[b * MM + m] * decay;
    if (m == idx) u += ws;
    usage_out[b * MM + m] = u;
  }
}

// ---------------------------------------------------------------------------
// Kernel 2: qp = query @ W (fp32 VALU GEMM); epilogue emits 3-way bf16 split.
// ---------------------------------------------------------------------------
#define BMq 64
#define BNq 64
#define BKq 32
#define PADq 4

__global__ __launch_bounds__(256) void gemm_nn_qp(
    const float* __restrict__ A, const float* __restrict__ Bw,
    unsigned short* __restrict__ q1, unsigned short* __restrict__ q2,
    unsigned short* __restrict__ q3) {
  __shared__ __align__(16) float As[BKq][BMq + PADq];
  __shared__ __align__(16) float Bs[BKq][BNq + PADq];
  const int tid = threadIdx.x;
  const int tx = tid & 15, ty = tid >> 4;
  const int i0 = blockIdx.y * BMq;
  const int j0 = blockIdx.x * BNq;
  float acc[4][4] = {{0.f}};
  for (int k0 = 0; k0 < DD; k0 += BKq) {
#pragma unroll
    for (int r = 0; r < 2; ++r) {
      int ff = tid + r * 256;
      int row = ff >> 3, kq = ff & 7;
      float4 v = *(const float4*)(A + (size_t)(i0 + row) * DD + k0 + kq * 4);
      As[kq * 4 + 0][row] = v.x; As[kq * 4 + 1][row] = v.y;
      As[kq * 4 + 2][row] = v.z; As[kq * 4 + 3][row] = v.w;
      int kr = ff >> 4, jq = ff & 15;
      float4 w = *(const float4*)(Bw + (size_t)(k0 + kr) * DD + j0 + jq * 4);
      *(float4*)&Bs[kr][jq * 4] = w;
    }
    __syncthreads();
#pragma unroll
    for (int k = 0; k < BKq; ++k) {
      float4 a = *(const float4*)&As[k][ty * 4];
      float4 bb = *(const float4*)&Bs[k][tx * 4];
      float av[4] = {a.x, a.y, a.z, a.w};
      float bv[4] = {bb.x, bb.y, bb.z, bb.w};
#pragma unroll
      for (int i = 0; i < 4; ++i)
#pragma unroll
        for (int j = 0; j < 4; ++j) acc[i][j] += av[i] * bv[j];
    }
    __syncthreads();
  }
#pragma unroll
  for (int i = 0; i < 4; ++i) {
    int row = i0 + ty * 4 + i;
    ushort4 v1, v2, v3;
    split3(acc[i][0], v1.x, v2.x, v3.x);
    split3(acc[i][1], v1.y, v2.y, v3.y);
    split3(acc[i][2], v1.z, v2.z, v3.z);
    split3(acc[i][3], v1.w, v2.w, v3.w);
    *(ushort4*)(q1 + (size_t)row * DD + j0 + tx * 4) = v1;
    *(ushort4*)(q2 + (size_t)row * DD + j0 + tx * 4) = v2;
    *(ushort4*)(q3 + (size_t)row * DD + j0 + tx * 4) = v3;
  }
}

// ---------------------------------------------------------------------------
// Kernel 3: scores via 3-way-split bf16 MFMA, 6 terms.
// Tile 128(S) x 128(M) x 32(K); 4 waves, each wave 32S x 128M (2 st x 8 jt),
// single 64-VGPR accumulator (small terms first within each k-step).
// Per wave/k-step: 96 MFMAs vs 30 ds_read_b128 -> MFMA-bound.
// memory fp32 -> 3x bf16 fused in staging (each element loaded once).
// ---------------------------------------------------------------------------
#define LSTR 40  // LDS row stride in bf16 elems (32 + 8 pad, 80 B)

__global__ __launch_bounds__(256, 1) void gemm_scores_mfma(
    const unsigned short* __restrict__ q1_g,
    const unsigned short* __restrict__ q2_g,
    const unsigned short* __restrict__ q3_g,
    const float* __restrict__ mem, float* __restrict__ sc_out) {
  __shared__ __align__(16) unsigned short q1_s[128 * LSTR];
  __shared__ __align__(16) unsigned short q2_s[128 * LSTR];
  __shared__ __align__(16) unsigned short q3_s[128 * LSTR];
  __shared__ __align__(16) unsigned short m1_s[128 * LSTR];
  __shared__ __align__(16) unsigned short m2_s[128 * LSTR];
  __shared__ __align__(16) unsigned short m3_s[128 * LSTR];
  const int tid = threadIdx.x;
  const int b = blockIdx.x & 7;                 // XCD-pinned batch
  const int j0 = (blockIdx.x >> 3) * 128;
  const int wv = tid >> 6, lane = tid & 63;
  const int quad = lane >> 4, r = lane & 15;

  // q staging: 128 rows x 4 chunks (uint4 = 8 bf16) per array; 2 chunks/thread
  const int qrow0 = tid >> 2, qc = tid & 3;
  const int qrow1 = 64 + (tid >> 2);
  const unsigned short* q1b = q1_g + (size_t)b * SS * DD;
  const unsigned short* q2b = q2_g + (size_t)b * SS * DD;
  const unsigned short* q3b = q3_g + (size_t)b * SS * DD;
  // m staging: 128 rows x 8 chunks (float4); 4 chunks/thread
  const int mrow = tid >> 3, mk = tid & 7;
  const float* mbase = mem + ((size_t)b * MM + j0) * DD;

  f32x4 acc[2][8];
#pragma unroll
  for (int i = 0; i < 2; ++i)
#pragma unroll
    for (int j = 0; j < 8; ++j)
#pragma unroll
      for (int c = 0; c < 4; ++c) acc[i][j][c] = 0.f;

  uint4 q1r0, q1r1, q2r0, q2r1, q3r0, q3r1;
  float4 mr[4];

  // prologue: k-step 0 loads
  q1r0 = *(const uint4*)(q1b + (size_t)qrow0 * DD + qc * 8);
  q1r1 = *(const uint4*)(q1b + (size_t)qrow1 * DD + qc * 8);
  q2r0 = *(const uint4*)(q2b + (size_t)qrow0 * DD + qc * 8);
  q2r1 = *(const uint4*)(q2b + (size_t)qrow1 * DD + qc * 8);
  q3r0 = *(const uint4*)(q3b + (size_t)qrow0 * DD + qc * 8);
  q3r1 = *(const uint4*)(q3b + (size_t)qrow1 * DD + qc * 8);
#pragma unroll
  for (int i = 0; i < 4; ++i)
    mr[i] = *(const float4*)(mbase + (size_t)(mrow + 32 * i) * DD + mk * 4);

  for (int ks = 0; ks < 16; ++ks) {
    if (ks) __syncthreads();
    *(uint4*)&q1_s[qrow0 * LSTR + qc * 8] = q1r0;
    *(uint4*)&q1_s[qrow1 * LSTR + qc * 8] = q1r1;
    *(uint4*)&q2_s[qrow0 * LSTR + qc * 8] = q2r0;
    *(uint4*)&q2_s[qrow1 * LSTR + qc * 8] = q2r1;
    *(uint4*)&q3_s[qrow0 * LSTR + qc * 8] = q3r0;
    *(uint4*)&q3_s[qrow1 * LSTR + qc * 8] = q3r1;
#pragma unroll
    for (int i = 0; i < 4; ++i) {
      ushort4 v1, v2, v3;
      split3(mr[i].x, v1.x, v2.x, v3.x);
      split3(mr[i].y, v1.y, v2.y, v3.y);
      split3(mr[i].z, v1.z, v2.z, v3.z);
      split3(mr[i].w, v1.w, v2.w, v3.w);
      int row = mrow + 32 * i;
      *(ushort4*)&m1_s[row * LSTR + mk * 4] = v1;
      *(ushort4*)&m2_s[row * LSTR + mk * 4] = v2;
      *(ushort4*)&m3_s[row * LSTR + mk * 4] = v3;
    }
    __syncthreads();
    if (ks < 15) {
      int k0 = (ks + 1) * 32;
      q1r0 = *(const uint4*)(q1b + (size_t)qrow0 * DD + k0 + qc * 8);
      q1r1 = *(const uint4*)(q1b + (size_t)qrow1 * DD + k0 + qc * 8);
      q2r0 = *(const uint4*)(q2b + (size_t)qrow0 * DD + k0 + qc * 8);
      q2r1 = *(const uint4*)(q2b + (size_t)qrow1 * DD + k0 + qc * 8);
      q3r0 = *(const uint4*)(q3b + (size_t)qrow0 * DD + k0 + qc * 8);
      q3r1 = *(const uint4*)(q3b + (size_t)qrow1 * DD + k0 + qc * 8);
#pragma unroll
      for (int i = 0; i < 4; ++i)
        mr[i] = *(const float4*)(mbase + (size_t)(mrow + 32 * i) * DD + k0 + mk * 4);
    }
    s16x8 a1[2], a2[2], a3[2];
#pragma unroll
    for (int st = 0; st < 2; ++st) {
      int arow = wv * 32 + st * 16 + r;
      a1[st] = *(const s16x8*)&q1_s[arow * LSTR + quad * 8];
      a2[st] = *(const s16x8*)&q2_s[arow * LSTR + quad * 8];
      a3[st] = *(const s16x8*)&q3_s[arow * LSTR + quad * 8];
    }
#pragma unroll
    for (int jt = 0; jt < 8; ++jt) {
      int brow = jt * 16 + r;
      s16x8 b1 = *(const s16x8*)&m1_s[brow * LSTR + quad * 8];
      s16x8 b2 = *(const s16x8*)&m2_s[brow * LSTR + quad * 8];
      s16x8 b3 = *(const s16x8*)&m3_s[brow * LSTR + quad * 8];
#pragma unroll
      for (int st = 0; st < 2; ++st) {
        acc[st][jt] = __builtin_amdgcn_mfma_f32_16x16x32_bf16(a1[st], b3, acc[st][jt], 0, 0, 0);
        acc[st][jt] = __builtin_amdgcn_mfma_f32_16x16x32_bf16(a3[st], b1, acc[st][jt], 0, 0, 0);
        acc[st][jt] = __builtin_amdgcn_mfma_f32_16x16x32_bf16(a2[st], b2, acc[st][jt], 0, 0, 0);
        acc[st][jt] = __builtin_amdgcn_mfma_f32_16x16x32_bf16(a1[st], b2, acc[st][jt], 0, 0, 0);
        acc[st][jt] = __builtin_amdgcn_mfma_f32_16x16x32_bf16(a2[st], b1, acc[st][jt], 0, 0, 0);
        acc[st][jt] = __builtin_amdgcn_mfma_f32_16x16x32_bf16(a1[st], b1, acc[st][jt], 0, 0, 0);
      }
    }
  }
  // epilogue: C/D layout col=lane&15, row=quad*4+reg
  const float scl = 0.04419417382415922f;  // 1/sqrt(512)
  float* C = sc_out + (size_t)b * SS * MM;
#pragma unroll
  for (int st = 0; st < 2; ++st)
#pragma unroll
    for (int jt = 0; jt < 8; ++jt)
#pragma unroll
      for (int reg = 0; reg < 4; ++reg) {
        int srow = wv * 32 + st * 16 + quad * 4 + reg;
        int scol = j0 + jt * 16 + r;
        C[(size_t)srow * MM + scol] = acc[st][jt][reg] * scl;
      }
}

// ---------------------------------------------------------------------------
// Kernel 4: per (b,s) row — mask, exact top-k threshold (radix select),
// softmax, dense attn write, retrieved gather.
// ---------------------------------------------------------------------------
__device__ __forceinline__ unsigned fkey(float f) {
  unsigned u = __float_as_uint(f);
  return (u & 0x80000000u) ? ~u : (u | 0x80000000u);
}
__device__ __forceinline__ float finv(unsigned u) {
  unsigned b = (u & 0x80000000u) ? (u & 0x7fffffffu) : ~u;
  return __uint_as_float(b);
}

__global__ __launch_bounds__(256) void select_kernel(
    const float* __restrict__ scores, const int* __restrict__ vmask,
    const int* __restrict__ widx, const int* __restrict__ topk,
    const float* __restrict__ memory, float* __restrict__ retrieved,
    float* __restrict__ attn) {
  __shared__ float sc[MM];
  __shared__ int kept[MM];
  __shared__ unsigned histw[4 * 256];
  __shared__ float red[256];
  __shared__ unsigned sh_pref;
  __shared__ int sh_k, sh_nkept;
  __shared__ float sh_zinv;

  const int tid = threadIdx.x;
  const int s = blockIdx.x, b = blockIdx.y;
  int wi = widx[b] % MM; if (wi < 0) wi += MM;
  const float4* srow4 = (const float4*)(scores + ((size_t)b * SS + s) * MM);
  const int4* vrow4 = (const int4*)(vmask + (size_t)b * MM);
  unsigned* hw = histw + (tid >> 6) * 256;

  if (tid == 0) { sh_pref = 0u; sh_nkept = 0; sh_k = topk[0]; }
  for (int i = tid; i < 1024; i += 256) histw[i] = 0u;
  __syncthreads();

  float lmax = -INFINITY;
  for (int m4 = tid; m4 < MM / 4; m4 += 256) {
    float4 v = srow4[m4];
    int4 mk = vrow4[m4];
    int mb = m4 * 4;
    if (!(mk.x || mb + 0 == wi)) v.x = -INFINITY;
    if (!(mk.y || mb + 1 == wi)) v.y = -INFINITY;
    if (!(mk.z || mb + 2 == wi)) v.z = -INFINITY;
    if (!(mk.w || mb + 3 == wi)) v.w = -INFINITY;
    ((float4*)sc)[m4] = v;
    lmax = fmaxf(lmax, fmaxf(fmaxf(v.x, v.y), fmaxf(v.z, v.w)));
    atomicAdd(&hw[fkey(v.x) >> 24], 1u);
    atomicAdd(&hw[fkey(v.y) >> 24], 1u);
    atomicAdd(&hw[fkey(v.z) >> 24], 1u);
    atomicAdd(&hw[fkey(v.w) >> 24], 1u);
  }
  red[tid] = lmax;
  __syncthreads();
#pragma unroll
  for (int off = 128; off > 0; off >>= 1) {
    if (tid < off) red[tid] = fmaxf(red[tid], red[tid + off]);
    __syncthreads();
  }
  const float maxv = red[0];

  for (int pass = 0; pass < 4; ++pass) {
    const int shift = 24 - pass * 8;
    if (pass > 0) {
      const unsigned pref = sh_pref;
      const unsigned hmask = 0xFFFFFFFFu << (shift + 8);
      for (int i = tid; i < 1024; i += 256) histw[i] = 0u;
      __syncthreads();
      for (int m = tid; m < MM; m += 256) {
        unsigned u = fkey(sc[m]);
        if ((u & hmask) == pref) atomicAdd(&hw[(u >> shift) & 0xFFu], 1u);
      }
      __syncthreads();
    }
    if (tid < 64) {
      const int l = tid;
      unsigned h0 = histw[l * 4 + 0] + histw[256 + l * 4 + 0] + histw[512 + l * 4 + 0] + histw[768 + l * 4 + 0];
      unsigned h1 = histw[l * 4 + 1] + histw[256 + l * 4 + 1] + histw[512 + l * 4 + 1] + histw[768 + l * 4 + 1];
      unsigned h2 = histw[l * 4 + 2] + histw[256 + l * 4 + 2] + histw[512 + l * 4 + 2] + histw[768 + l * 4 + 2];
      unsigned h3 = histw[l * 4 + 3] + histw[256 + l * 4 + 3] + histw[512 + l * 4 + 3] + histw[768 + l * 4 + 3];
      unsigned lsum = h0 + h1 + h2 + h3;
      unsigned g = lsum;
#pragma unroll
      for (int off = 1; off < 64; off <<= 1) {
        unsigned t = __shfl_down(g, off, 64);
        if (l + off < 64) g += t;
      }
      unsigned above = g - lsum;
      unsigned suf3 = h3 + above;
      unsigned suf2 = h2 + suf3;
      unsigned suf1 = h1 + suf2;
      unsigned suf0 = h0 + suf1;
      const unsigned kk = (unsigned)sh_k;
      const unsigned prefc = sh_pref;
      unsigned ge, geN;
      ge = suf0; geN = suf1;
      if (ge >= kk && geN < kk) { sh_pref = prefc | ((unsigned)(4 * l + 0) << shift); sh_k = (int)(kk - geN); }
      ge = suf1; geN = suf2;
      if (ge >= kk && geN < kk) { sh_pref = prefc | ((unsigned)(4 * l + 1) << shift); sh_k = (int)(kk - geN); }
      ge = suf2; geN = suf3;
      if (ge >= kk && geN < kk) { sh_pref = prefc | ((unsigned)(4 * l + 2) << shift); sh_k = (int)(kk - geN); }
      ge = suf3; geN = above;
      if (ge >= kk && geN < kk) { sh_pref = prefc | ((unsigned)(4 * l + 3) << shift); sh_k = (int)(kk - geN); }
    }
    __syncthreads();
  }
  const float thr = finv(sh_pref);

  float lz = 0.f;
  for (int m4 = tid; m4 < MM / 4; m4 += 256) {
    float4 v = ((float4*)sc)[m4];
    v.x = (v.x >= thr) ? __expf(v.x - maxv) : 0.f;
    v.y = (v.y >= thr) ? __expf(v.y - maxv) : 0.f;
    v.z = (v.z >= thr) ? __expf(v.z - maxv) : 0.f;
    v.w = (v.w >= thr) ? __expf(v.w - maxv) : 0.f;
    ((float4*)sc)[m4] = v;
    lz += v.x + v.y + v.z + v.w;
  }
  red[tid] = lz;
  __syncthreads();
#pragma unroll
  for (int off = 128; off > 0; off >>= 1) {
    if (tid < off) red[tid] += red[tid + off];
    __syncthreads();
  }
  if (tid == 0) sh_zinv = 1.0f / red[0];
  __syncthreads();
  const float zinv = sh_zinv;

  float4* arow4 = (float4*)(attn + ((size_t)b * SS + s) * MM);
  for (int m4 = tid; m4 < MM / 4; m4 += 256) {
    float4 p = ((float4*)sc)[m4];
    float4 o = make_float4(p.x * zinv, p.y * zinv, p.z * zinv, p.w * zinv);
    arow4[m4] = o;
    int mb = m4 * 4;
    if (p.x > 0.f) kept[atomicAdd(&sh_nkept, 1)] = mb + 0;
    if (p.y > 0.f) kept[atomicAdd(&sh_nkept, 1)] = mb + 1;
    if (p.z > 0.f) kept[atomicAdd(&sh_nkept, 1)] = mb + 2;
    if (p.w > 0.f) kept[atomicAdd(&sh_nkept, 1)] = mb + 3;
  }
  __syncthreads();
  const int nk = sh_nkept;

  float a0 = 0.f, a1 = 0.f;
  const float* mb_ = memory + (size_t)b * MM * DD;
  int i = 0;
  for (; i + 4 <= nk; i += 4) {
    int m0 = kept[i], m1 = kept[i + 1], m2 = kept[i + 2], m3 = kept[i + 3];
    float p0 = sc[m0], p1 = sc[m1], p2 = sc[m2], p3 = sc[m3];
    const float* r0 = mb_ + (size_t)m0 * DD;
    const float* r1 = mb_ + (size_t)m1 * DD;
    const float* r2 = mb_ + (size_t)m2 * DD;
    const float* r3 = mb_ + (size_t)m3 * DD;
    float v0a = r0[tid], v0b = r0[tid + 256];
    float v1a = r1[tid], v1b = r1[tid + 256];
    float v2a = r2[tid], v2b = r2[tid + 256];
    float v3a = r3[tid], v3b = r3[tid + 256];
    a0 += p0 * v0a + p1 * v1a + p2 * v2a + p3 * v3a;
    a1 += p0 * v0b + p1 * v1b + p2 * v2b + p3 * v3b;
  }
  for (; i < nk; ++i) {
    int m = kept[i];
    float p = sc[m];
    const float* mr = mb_ + (size_t)m * DD;
    a0 += p * mr[tid];
    a1 += p * mr[tid + 256];
  }
  float* rrow = retrieved + ((size_t)b * SS + s) * DD;
  rrow[tid] = a0 * zinv;
  rrow[tid + 256] = a1 * zinv;
}

// ---------------------------------------------------------------------------
extern "C" void kernel_launch(void* const* d_in, const int* in_sizes, int n_in,
                              void* d_out, int out_size, void* d_ws,
                              size_t ws_size, hipStream_t stream) {
  float* memory = (float*)d_in[0];
  const float* usage = (const float*)d_in[1];
  const float* content = (const float*)d_in[2];
  const float* wstr = (const float*)d_in[3];
  const float* query = (const float*)d_in[4];
  const float* W = (const float*)d_in[5];
  const float* ttab = (const float*)d_in[6];
  const float* decay = (const float*)d_in[7];
  const int* vmask = (const int*)d_in[8];
  const int* widx = (const int*)d_in[9];
  const int* topk = (const int*)d_in[10];

  float* out = (float*)d_out;
  float* retrieved = out;                              // B*S*D floats
  float* attn = out + (size_t)BB * SS * DD;            // B*S*M floats
  float* usage_out = attn + (size_t)BB * SS * MM;      // B*M floats

  const size_t qsz = (size_t)BB * SS * DD;             // elems per q array
  float* scores = (float*)d_ws;                        // 16 MB
  unsigned short* q1 = (unsigned short*)(scores + (size_t)BB * SS * MM);
  unsigned short* q2 = q1 + qsz;
  unsigned short* q3;
  size_t need3 = (size_t)BB * SS * MM * 4 + 3 * qsz * 2;
  if (ws_size >= need3) {
    q3 = q2 + qsz;  // fits in workspace
  } else {
    // carve the tail of the attn output region (select overwrites it later;
    // same-stream ordering makes this safe)
    q3 = (unsigned short*)(attn + (size_t)BB * SS * MM) - qsz;
  }

  update_kernel<<<BB, 256, 0, stream>>>(memory, usage, content, wstr, ttab,
                                        decay, widx, usage_out);
  gemm_nn_qp<<<dim3(DD / BNq, (BB * SS) / BMq), 256, 0, stream>>>(query, W, q1,
                                                                  q2, q3);
  gemm_scores_mfma<<<dim3((MM / 128) * BB), 256, 0, stream>>>(q1, q2, q3,
                                                              memory, scores);
  select_kernel<<<dim3(SS, BB), 256, 0, stream>>>(scores, vmask, widx, topk,
                                                  memory, retrieved, attn);
}

// Round 6
// 201.903 us; speedup vs baseline: 1.2239x; 1.0074x over previous
//
#include <hip/hip_runtime.h>
#include <hip/hip_bf16.h>
#include <math.h>

#define BB 8
#define MM 4096
#define DD 512
#define SS 128

typedef _Float16 f16;
typedef _Float16 f16x4 __attribute__((ext_vector_type(4)));
typedef _Float16 f16x8 __attribute__((ext_vector_type(8)));
typedef float f32x4 __attribute__((ext_vector_type(4)));

struct f16pair { f16 h; f16 l; };
// 2-way f16 split: x ~= h + l, residual <= 2^-22 |x|
__device__ __forceinline__ f16pair split2(float x) {
  f16pair p;
  p.h = (f16)x;
  p.l = (f16)(x - (float)p.h);
  return p;
}

// ---------------------------------------------------------------------------
// Kernel 1: memory row write + usage decay
// ---------------------------------------------------------------------------
__global__ __launch_bounds__(256) void update_kernel(
    float* __restrict__ memory, const float* __restrict__ usage,
    const float* __restrict__ content, const float* __restrict__ wstr,
    const float* __restrict__ ttab, const float* __restrict__ decay_p,
    const int* __restrict__ widx, float* __restrict__ usage_out) {
  const int b = blockIdx.x;
  int idx = widx[b] % MM; if (idx < 0) idx += MM;
  const float ws = wstr[b];
  const float decay = decay_p[0];
  for (int d = threadIdx.x; d < DD; d += blockDim.x) {
    float cw = content[b * DD + d] + ttab[(size_t)idx * DD + d];
    size_t off = (size_t)b * MM * DD + (size_t)idx * DD + d;
    float old = memory[off];
    memory[off] = old * (1.0f - ws) + cw * ws;
  }
  for (int m = threadIdx.x; m < MM; m += blockDim.x) {
    float u = usage[b * MM + m] * decay;
    if (m == idx) u += ws;
    usage_out[b * MM + m] = u;
  }
}

// ---------------------------------------------------------------------------
// Kernel 2: qp = query @ W via f16 3-term MFMA. 64R x 64N x 32K tiles,
// grid 8x16 = 128 blocks. W tile is transposed + split2 into LDS. Epilogue
// emits the 2-way f16 split of qp directly.
// ---------------------------------------------------------------------------
#define QLSTR 40  // LDS row stride in f16 elems

__global__ __launch_bounds__(256) void gemm_qp_mfma(
    const float* __restrict__ query, const float* __restrict__ W,
    f16* __restrict__ q1, f16* __restrict__ q2) {
  __shared__ __align__(16) f16 A1s[64 * QLSTR];
  __shared__ __align__(16) f16 A2s[64 * QLSTR];
  __shared__ __align__(16) f16 B1s[64 * QLSTR];
  __shared__ __align__(16) f16 B2s[64 * QLSTR];
  const int tid = threadIdx.x;
  const int n0 = blockIdx.x * 64;
  const int r0 = blockIdx.y * 64;
  const int wv = tid >> 6, lane = tid & 63;
  const int quad = lane >> 4, rr = lane & 15;
  const int wr = wv & 1, wc = wv >> 1;

  // A staging: 64 rows x 8 float4 = 512 chunks, 2/thread
  const int arow = tid >> 3, ak = tid & 7;
  // B staging: 32 k-rows x 16 float4 = 512 chunks, 2/thread
  const int bkr = tid >> 4, bnq = tid & 15;

  f32x4 acc[2][2];
#pragma unroll
  for (int i = 0; i < 2; ++i)
#pragma unroll
    for (int j = 0; j < 2; ++j)
#pragma unroll
      for (int c = 0; c < 4; ++c) acc[i][j][c] = 0.f;

  float4 ar0, ar1, br0, br1;
  ar0 = *(const float4*)(query + (size_t)(r0 + arow) * DD + ak * 4);
  ar1 = *(const float4*)(query + (size_t)(r0 + arow + 32) * DD + ak * 4);
  br0 = *(const float4*)(W + (size_t)bkr * DD + n0 + bnq * 4);
  br1 = *(const float4*)(W + (size_t)(bkr + 16) * DD + n0 + bnq * 4);

  for (int ks = 0; ks < 16; ++ks) {
    if (ks) __syncthreads();
    {
      f16x4 h, l;
      f16pair p;
      p = split2(ar0.x); h[0] = p.h; l[0] = p.l;
      p = split2(ar0.y); h[1] = p.h; l[1] = p.l;
      p = split2(ar0.z); h[2] = p.h; l[2] = p.l;
      p = split2(ar0.w); h[3] = p.h; l[3] = p.l;
      *(f16x4*)&A1s[arow * QLSTR + ak * 4] = h;
      *(f16x4*)&A2s[arow * QLSTR + ak * 4] = l;
      p = split2(ar1.x); h[0] = p.h; l[0] = p.l;
      p = split2(ar1.y); h[1] = p.h; l[1] = p.l;
      p = split2(ar1.z); h[2] = p.h; l[2] = p.l;
      p = split2(ar1.w); h[3] = p.h; l[3] = p.l;
      *(f16x4*)&A1s[(arow + 32) * QLSTR + ak * 4] = h;
      *(f16x4*)&A2s[(arow + 32) * QLSTR + ak * 4] = l;
      float wv4[4] = {br0.x, br0.y, br0.z, br0.w};
#pragma unroll
      for (int i = 0; i < 4; ++i) {
        f16pair q = split2(wv4[i]);
        B1s[(bnq * 4 + i) * QLSTR + bkr] = q.h;
        B2s[(bnq * 4 + i) * QLSTR + bkr] = q.l;
      }
      float wv5[4] = {br1.x, br1.y, br1.z, br1.w};
#pragma unroll
      for (int i = 0; i < 4; ++i) {
        f16pair q = split2(wv5[i]);
        B1s[(bnq * 4 + i) * QLSTR + bkr + 16] = q.h;
        B2s[(bnq * 4 + i) * QLSTR + bkr + 16] = q.l;
      }
    }
    __syncthreads();
    if (ks < 15) {
      int k0 = (ks + 1) * 32;
      ar0 = *(const float4*)(query + (size_t)(r0 + arow) * DD + k0 + ak * 4);
      ar1 = *(const float4*)(query + (size_t)(r0 + arow + 32) * DD + k0 + ak * 4);
      br0 = *(const float4*)(W + (size_t)(k0 + bkr) * DD + n0 + bnq * 4);
      br1 = *(const float4*)(W + (size_t)(k0 + bkr + 16) * DD + n0 + bnq * 4);
    }
    f16x8 a1[2], a2[2];
#pragma unroll
    for (int st = 0; st < 2; ++st) {
      int row = wr * 32 + st * 16 + rr;
      a1[st] = *(const f16x8*)&A1s[row * QLSTR + quad * 8];
      a2[st] = *(const f16x8*)&A2s[row * QLSTR + quad * 8];
    }
#pragma unroll
    for (int ct = 0; ct < 2; ++ct) {
      int col = wc * 32 + ct * 16 + rr;
      f16x8 b1 = *(const f16x8*)&B1s[col * QLSTR + quad * 8];
      f16x8 b2 = *(const f16x8*)&B2s[col * QLSTR + quad * 8];
#pragma unroll
      for (int st = 0; st < 2; ++st) {
        acc[st][ct] = __builtin_amdgcn_mfma_f32_16x16x32_f16(a1[st], b2, acc[st][ct], 0, 0, 0);
        acc[st][ct] = __builtin_amdgcn_mfma_f32_16x16x32_f16(a2[st], b1, acc[st][ct], 0, 0, 0);
        acc[st][ct] = __builtin_amdgcn_mfma_f32_16x16x32_f16(a1[st], b1, acc[st][ct], 0, 0, 0);
      }
    }
  }
  // epilogue: C/D layout col=lane&15, row=quad*4+reg; emit split2(qp)
#pragma unroll
  for (int st = 0; st < 2; ++st)
#pragma unroll
    for (int ct = 0; ct < 2; ++ct)
#pragma unroll
      for (int reg = 0; reg < 4; ++reg) {
        int row = r0 + wr * 32 + st * 16 + quad * 4 + reg;
        int col = n0 + wc * 32 + ct * 16 + rr;
        f16pair p = split2(acc[st][ct][reg]);
        q1[(size_t)row * DD + col] = p.h;
        q2[(size_t)row * DD + col] = p.l;
      }
}

// ---------------------------------------------------------------------------
// Kernel 3: scores via f16 2-way-split MFMA, 3 terms.
// Tile 128(S) x 64(M) x 32(K), grid 512 (2 blocks/CU). Waves split S
// 4-ways (32S x 64M each) -> q fragments are wave-private: loaded DIRECTLY
// from global (L2-resident, XCD-pinned), no q LDS at all. Only memory is
// staged in LDS (fp32 -> split2 f16 fused, each element read once).
// ---------------------------------------------------------------------------
#define LSTR 40  // LDS row stride in f16 elems

__global__ __launch_bounds__(256, 2) void gemm_scores_mfma(
    const f16* __restrict__ q1_g, const f16* __restrict__ q2_g,
    const float* __restrict__ mem, float* __restrict__ sc_out) {
  __shared__ __align__(16) f16 m1_s[64 * LSTR];
  __shared__ __align__(16) f16 m2_s[64 * LSTR];
  const int tid = threadIdx.x;
  const int b = blockIdx.x & 7;                 // XCD-pinned batch
  const int j0 = (blockIdx.x >> 3) * 64;
  const int wv = tid >> 6, lane = tid & 63;
  const int quad = lane >> 4, rr = lane & 15;

  const f16* q1b = q1_g + (size_t)b * SS * DD;
  const f16* q2b = q2_g + (size_t)b * SS * DD;
  // m staging: 64 rows x 8 float4 = 512 chunks, 2/thread
  const int mrow = tid >> 3, mk = tid & 7;
  const float* mbase = mem + ((size_t)b * MM + j0) * DD;

  f32x4 acc[2][4];
#pragma unroll
  for (int i = 0; i < 2; ++i)
#pragma unroll
    for (int j = 0; j < 4; ++j)
#pragma unroll
      for (int c = 0; c < 4; ++c) acc[i][j][c] = 0.f;

  float4 mr0, mr1;
  f16x8 a1c[2], a2c[2], a1n[2], a2n[2];

  // prologue: k-step 0
  mr0 = *(const float4*)(mbase + (size_t)mrow * DD + mk * 4);
  mr1 = *(const float4*)(mbase + (size_t)(mrow + 32) * DD + mk * 4);
#pragma unroll
  for (int st = 0; st < 2; ++st) {
    int srow = wv * 32 + st * 16 + rr;
    a1c[st] = *(const f16x8*)(q1b + (size_t)srow * DD + quad * 8);
    a2c[st] = *(const f16x8*)(q2b + (size_t)srow * DD + quad * 8);
  }

  for (int ks = 0; ks < 16; ++ks) {
    if (ks) __syncthreads();
    {
      f16x4 h, l;
      f16pair p;
      p = split2(mr0.x); h[0] = p.h; l[0] = p.l;
      p = split2(mr0.y); h[1] = p.h; l[1] = p.l;
      p = split2(mr0.z); h[2] = p.h; l[2] = p.l;
      p = split2(mr0.w); h[3] = p.h; l[3] = p.l;
      *(f16x4*)&m1_s[mrow * LSTR + mk * 4] = h;
      *(f16x4*)&m2_s[mrow * LSTR + mk * 4] = l;
      p = split2(mr1.x); h[0] = p.h; l[0] = p.l;
      p = split2(mr1.y); h[1] = p.h; l[1] = p.l;
      p = split2(mr1.z); h[2] = p.h; l[2] = p.l;
      p = split2(mr1.w); h[3] = p.h; l[3] = p.l;
      *(f16x4*)&m1_s[(mrow + 32) * LSTR + mk * 4] = h;
      *(f16x4*)&m2_s[(mrow + 32) * LSTR + mk * 4] = l;
    }
    __syncthreads();
    if (ks < 15) {
      int k0 = (ks + 1) * 32;
      mr0 = *(const float4*)(mbase + (size_t)mrow * DD + k0 + mk * 4);
      mr1 = *(const float4*)(mbase + (size_t)(mrow + 32) * DD + k0 + mk * 4);
#pragma unroll
      for (int st = 0; st < 2; ++st) {
        int srow = wv * 32 + st * 16 + rr;
        a1n[st] = *(const f16x8*)(q1b + (size_t)srow * DD + k0 + quad * 8);
        a2n[st] = *(const f16x8*)(q2b + (size_t)srow * DD + k0 + quad * 8);
      }
    }
#pragma unroll
    for (int jt = 0; jt < 4; ++jt) {
      int brow = jt * 16 + rr;
      f16x8 b1 = *(const f16x8*)&m1_s[brow * LSTR + quad * 8];
      f16x8 b2 = *(const f16x8*)&m2_s[brow * LSTR + quad * 8];
#pragma unroll
      for (int st = 0; st < 2; ++st) {
        acc[st][jt] = __builtin_amdgcn_mfma_f32_16x16x32_f16(a1c[st], b2, acc[st][jt], 0, 0, 0);
        acc[st][jt] = __builtin_amdgcn_mfma_f32_16x16x32_f16(a2c[st], b1, acc[st][jt], 0, 0, 0);
        acc[st][jt] = __builtin_amdgcn_mfma_f32_16x16x32_f16(a1c[st], b1, acc[st][jt], 0, 0, 0);
      }
    }
#pragma unroll
    for (int st = 0; st < 2; ++st) {
      a1c[st] = a1n[st];
      a2c[st] = a2n[st];
    }
  }
  // epilogue: C/D layout col=lane&15, row=quad*4+reg
  const float scl = 0.04419417382415922f;  // 1/sqrt(512)
  float* C = sc_out + (size_t)b * SS * MM;
#pragma unroll
  for (int st = 0; st < 2; ++st)
#pragma unroll
    for (int jt = 0; jt < 4; ++jt)
#pragma unroll
      for (int reg = 0; reg < 4; ++reg) {
        int srow = wv * 32 + st * 16 + quad * 4 + reg;
        int scol = j0 + jt * 16 + rr;
        C[(size_t)srow * MM + scol] = acc[st][jt][reg] * scl;
      }
}

// ---------------------------------------------------------------------------
// Kernel 4: per (b,s) row — mask, exact top-k threshold (radix select),
// softmax, dense attn write, retrieved gather.
// ---------------------------------------------------------------------------
__device__ __forceinline__ unsigned fkey(float f) {
  unsigned u = __float_as_uint(f);
  return (u & 0x80000000u) ? ~u : (u | 0x80000000u);
}
__device__ __forceinline__ float finv(unsigned u) {
  unsigned b = (u & 0x80000000u) ? (u & 0x7fffffffu) : ~u;
  return __uint_as_float(b);
}

__global__ __launch_bounds__(256) void select_kernel(
    const float* __restrict__ scores, const int* __restrict__ vmask,
    const int* __restrict__ widx, const int* __restrict__ topk,
    const float* __restrict__ memory, float* __restrict__ retrieved,
    float* __restrict__ attn) {
  __shared__ float sc[MM];
  __shared__ int kept[MM];
  __shared__ unsigned histw[4 * 256];
  __shared__ float red[256];
  __shared__ unsigned sh_pref;
  __shared__ int sh_k, sh_nkept;
  __shared__ float sh_zinv;

  const int tid = threadIdx.x;
  const int s = blockIdx.x, b = blockIdx.y;
  int wi = widx[b] % MM; if (wi < 0) wi += MM;
  const float4* srow4 = (const float4*)(scores + ((size_t)b * SS + s) * MM);
  const int4* vrow4 = (const int4*)(vmask + (size_t)b * MM);
  unsigned* hw = histw + (tid >> 6) * 256;

  if (tid == 0) { sh_pref = 0u; sh_nkept = 0; sh_k = topk[0]; }
  for (int i = tid; i < 1024; i += 256) histw[i] = 0u;
  __syncthreads();

  float lmax = -INFINITY;
  for (int m4 = tid; m4 < MM / 4; m4 += 256) {
    float4 v = srow4[m4];
    int4 mk = vrow4[m4];
    int mb = m4 * 4;
    if (!(mk.x || mb + 0 == wi)) v.x = -INFINITY;
    if (!(mk.y || mb + 1 == wi)) v.y = -INFINITY;
    if (!(mk.z || mb + 2 == wi)) v.z = -INFINITY;
    if (!(mk.w || mb + 3 == wi)) v.w = -INFINITY;
    ((float4*)sc)[m4] = v;
    lmax = fmaxf(lmax, fmaxf(fmaxf(v.x, v.y), fmaxf(v.z, v.w)));
    atomicAdd(&hw[fkey(v.x) >> 24], 1u);
    atomicAdd(&hw[fkey(v.y) >> 24], 1u);
    atomicAdd(&hw[fkey(v.z) >> 24], 1u);
    atomicAdd(&hw[fkey(v.w) >> 24], 1u);
  }
  red[tid] = lmax;
  __syncthreads();
#pragma unroll
  for (int off = 128; off > 0; off >>= 1) {
    if (tid < off) red[tid] = fmaxf(red[tid], red[tid + off]);
    __syncthreads();
  }
  const float maxv = red[0];

  for (int pass = 0; pass < 4; ++pass) {
    const int shift = 24 - pass * 8;
    if (pass > 0) {
      const unsigned pref = sh_pref;
      const unsigned hmask = 0xFFFFFFFFu << (shift + 8);
      for (int i = tid; i < 1024; i += 256) histw[i] = 0u;
      __syncthreads();
      for (int m = tid; m < MM; m += 256) {
        unsigned u = fkey(sc[m]);
        if ((u & hmask) == pref) atomicAdd(&hw[(u >> shift) & 0xFFu], 1u);
      }
      __syncthreads();
    }
    if (tid < 64) {
      const int l = tid;
      unsigned h0 = histw[l * 4 + 0] + histw[256 + l * 4 + 0] + histw[512 + l * 4 + 0] + histw[768 + l * 4 + 0];
      unsigned h1 = histw[l * 4 + 1] + histw[256 + l * 4 + 1] + histw[512 + l * 4 + 1] + histw[768 + l * 4 + 1];
      unsigned h2 = histw[l * 4 + 2] + histw[256 + l * 4 + 2] + histw[512 + l * 4 + 2] + histw[768 + l * 4 + 2];
      unsigned h3 = histw[l * 4 + 3] + histw[256 + l * 4 + 3] + histw[512 + l * 4 + 3] + histw[768 + l * 4 + 3];
      unsigned lsum = h0 + h1 + h2 + h3;
      unsigned g = lsum;
#pragma unroll
      for (int off = 1; off < 64; off <<= 1) {
        unsigned t = __shfl_down(g, off, 64);
        if (l + off < 64) g += t;
      }
      unsigned above = g - lsum;
      unsigned suf3 = h3 + above;
      unsigned suf2 = h2 + suf3;
      unsigned suf1 = h1 + suf2;
      unsigned suf0 = h0 + suf1;
      const unsigned kk = (unsigned)sh_k;
      const unsigned prefc = sh_pref;
      unsigned ge, geN;
      ge = suf0; geN = suf1;
      if (ge >= kk && geN < kk) { sh_pref = prefc | ((unsigned)(4 * l + 0) << shift); sh_k = (int)(kk - geN); }
      ge = suf1; geN = suf2;
      if (ge >= kk && geN < kk) { sh_pref = prefc | ((unsigned)(4 * l + 1) << shift); sh_k = (int)(kk - geN); }
      ge = suf2; geN = suf3;
      if (ge >= kk && geN < kk) { sh_pref = prefc | ((unsigned)(4 * l + 2) << shift); sh_k = (int)(kk - geN); }
      ge = suf3; geN = above;
      if (ge >= kk && geN < kk) { sh_pref = prefc | ((unsigned)(4 * l + 3) << shift); sh_k = (int)(kk - geN); }
    }
    __syncthreads();
  }
  const float thr = finv(sh_pref);

  float lz = 0.f;
  for (int m4 = tid; m4 < MM / 4; m4 += 256) {
    float4 v = ((float4*)sc)[m4];
    v.x = (v.x >= thr) ? __expf(v.x - maxv) : 0.f;
    v.y = (v.y >= thr) ? __expf(v.y - maxv) : 0.f;
    v.z = (v.z >= thr) ? __expf(v.z - maxv) : 0.f;
    v.w = (v.w >= thr) ? __expf(v.w - maxv) : 0.f;
    ((float4*)sc)[m4] = v;
    lz += v.x + v.y + v.z + v.w;
  }
  red[tid] = lz;
  __syncthreads();
#pragma unroll
  for (int off = 128; off > 0; off >>= 1) {
    if (tid < off) red[tid] += red[tid + off];
    __syncthreads();
  }
  if (tid == 0) sh_zinv = 1.0f / red[0];
  __syncthreads();
  const float zinv = sh_zinv;

  float4* arow4 = (float4*)(attn + ((size_t)b * SS + s) * MM);
  for (int m4 = tid; m4 < MM / 4; m4 += 256) {
    float4 p = ((float4*)sc)[m4];
    float4 o = make_float4(p.x * zinv, p.y * zinv, p.z * zinv, p.w * zinv);
    arow4[m4] = o;
    int mb = m4 * 4;
    if (p.x > 0.f) kept[atomicAdd(&sh_nkept, 1)] = mb + 0;
    if (p.y > 0.f) kept[atomicAdd(&sh_nkept, 1)] = mb + 1;
    if (p.z > 0.f) kept[atomicAdd(&sh_nkept, 1)] = mb + 2;
    if (p.w > 0.f) kept[atomicAdd(&sh_nkept, 1)] = mb + 3;
  }
  __syncthreads();
  const int nk = sh_nkept;

  float a0 = 0.f, a1 = 0.f;
  const float* mb_ = memory + (size_t)b * MM * DD;
  int i = 0;
  for (; i + 4 <= nk; i += 4) {
    int m0 = kept[i], m1 = kept[i + 1], m2 = kept[i + 2], m3 = kept[i + 3];
    float p0 = sc[m0], p1 = sc[m1], p2 = sc[m2], p3 = sc[m3];
    const float* r0 = mb_ + (size_t)m0 * DD;
    const float* r1 = mb_ + (size_t)m1 * DD;
    const float* r2 = mb_ + (size_t)m2 * DD;
    const float* r3 = mb_ + (size_t)m3 * DD;
    float v0a = r0[tid], v0b = r0[tid + 256];
    float v1a = r1[tid], v1b = r1[tid + 256];
    float v2a = r2[tid], v2b = r2[tid + 256];
    float v3a = r3[tid], v3b = r3[tid + 256];
    a0 += p0 * v0a + p1 * v1a + p2 * v2a + p3 * v3a;
    a1 += p0 * v0b + p1 * v1b + p2 * v2b + p3 * v3b;
  }
  for (; i < nk; ++i) {
    int m = kept[i];
    float p = sc[m];
    const float* mr = mb_ + (size_t)m * DD;
    a0 += p * mr[tid];
    a1 += p * mr[tid + 256];
  }
  float* rrow = retrieved + ((size_t)b * SS + s) * DD;
  rrow[tid] = a0 * zinv;
  rrow[tid + 256] = a1 * zinv;
}

// ---------------------------------------------------------------------------
extern "C" void kernel_launch(void* const* d_in, const int* in_sizes, int n_in,
                              void* d_out, int out_size, void* d_ws,
                              size_t ws_size, hipStream_t stream) {
  float* memory = (float*)d_in[0];
  const float* usage = (const float*)d_in[1];
  const float* content = (const float*)d_in[2];
  const float* wstr = (const float*)d_in[3];
  const float* query = (const float*)d_in[4];
  const float* W = (const float*)d_in[5];
  const float* ttab = (const float*)d_in[6];
  const float* decay = (const float*)d_in[7];
  const int* vmask = (const int*)d_in[8];
  const int* widx = (const int*)d_in[9];
  const int* topk = (const int*)d_in[10];

  float* out = (float*)d_out;
  float* retrieved = out;                              // B*S*D floats
  float* attn = out + (size_t)BB * SS * DD;            // B*S*M floats
  float* usage_out = attn + (size_t)BB * SS * MM;      // B*M floats

  const size_t qsz = (size_t)BB * SS * DD;             // elems per q array
  float* scores = (float*)d_ws;                        // 16 MB
  f16* q1;
  f16* q2;
  size_t need = (size_t)BB * SS * MM * 4 + 2 * qsz * 2;
  if (ws_size >= need) {
    q1 = (f16*)(scores + (size_t)BB * SS * MM);
    q2 = q1 + qsz;
  } else {
    // carve tail of the attn output region (select overwrites it later;
    // same-stream ordering makes this safe)
    q2 = (f16*)(attn + (size_t)BB * SS * MM) - qsz;
    q1 = q2 - qsz;
  }

  update_kernel<<<BB, 256, 0, stream>>>(memory, usage, content, wstr, ttab,
                                        decay, widx, usage_out);
  gemm_qp_mfma<<<dim3(DD / 64, (BB * SS) / 64), 256, 0, stream>>>(query, W, q1,
                                                                  q2);
  gemm_scores_mfma<<<dim3((MM / 64) * BB), 256, 0, stream>>>(q1, q2, memory,
                                                             scores);
  select_kernel<<<dim3(SS, BB), 256, 0, stream>>>(scores, vmask, widx, topk,
                                                  memory, retrieved, attn);
}

// Round 7
// 180.776 us; speedup vs baseline: 1.3669x; 1.1169x over previous
//
#include <hip/hip_runtime.h>
#include <hip/hip_bf16.h>
#include <math.h>

#define BB 8
#define MM 4096
#define DD 512
#define SS 128

typedef _Float16 f16;
typedef _Float16 f16x4 __attribute__((ext_vector_type(4)));
typedef _Float16 f16x8 __attribute__((ext_vector_type(8)));
typedef float f32x4 __attribute__((ext_vector_type(4)));

struct f16pair { f16 h; f16 l; };
// 2-way f16 split: x ~= h + l, residual <= 2^-22 |x|
__device__ __forceinline__ f16pair split2(float x) {
  f16pair p;
  p.h = (f16)x;
  p.l = (f16)(x - (float)p.h);
  return p;
}

// split a float4 into two f16x4 and store to LDS
__device__ __forceinline__ void split_store4(float4 v, f16* p1, f16* p2) {
  f16x4 h, l;
  f16pair p;
  p = split2(v.x); h[0] = p.h; l[0] = p.l;
  p = split2(v.y); h[1] = p.h; l[1] = p.l;
  p = split2(v.z); h[2] = p.h; l[2] = p.l;
  p = split2(v.w); h[3] = p.h; l[3] = p.l;
  *(f16x4*)p1 = h;
  *(f16x4*)p2 = l;
}

// load 8 consecutive fp32 and split into two f16x8 fragments
__device__ __forceinline__ void cvt8(const float* p, f16x8& h, f16x8& l) {
  float4 v0 = *(const float4*)p;
  float4 v1 = *(const float4*)(p + 4);
  f16pair q;
  q = split2(v0.x); h[0] = q.h; l[0] = q.l;
  q = split2(v0.y); h[1] = q.h; l[1] = q.l;
  q = split2(v0.z); h[2] = q.h; l[2] = q.l;
  q = split2(v0.w); h[3] = q.h; l[3] = q.l;
  q = split2(v1.x); h[4] = q.h; l[4] = q.l;
  q = split2(v1.y); h[5] = q.h; l[5] = q.l;
  q = split2(v1.z); h[6] = q.h; l[6] = q.l;
  q = split2(v1.w); h[7] = q.h; l[7] = q.l;
}

// ---------------------------------------------------------------------------
// Kernel 1 (fused): blocks 0..7 = memory row write + usage decay;
// blocks 8..263 = qp = query @ W via f16 3-term MFMA (64R x 32N x 32K tiles,
// 256 blocks). A-fragments loaded directly from global (query is small and
// L2/L3-hot); W tile transposed+split into double-buffered LDS; one barrier
// per k-step. Epilogue emits split2(qp) into q1/q2.
// ---------------------------------------------------------------------------
#define QLSTR 40  // LDS row stride in f16 elems

__global__ __launch_bounds__(256) void prep_kernel(
    float* __restrict__ memory, const float* __restrict__ usage,
    const float* __restrict__ content, const float* __restrict__ wstr,
    const float* __restrict__ ttab, const float* __restrict__ decay_p,
    const int* __restrict__ widx, float* __restrict__ usage_out,
    const float* __restrict__ query, const float* __restrict__ W,
    f16* __restrict__ q1, f16* __restrict__ q2) {
  __shared__ __align__(16) f16 B1s[2][32 * QLSTR];
  __shared__ __align__(16) f16 B2s[2][32 * QLSTR];
  const int tid = threadIdx.x;

  if (blockIdx.x < 8) {  // ---- update part ----
    const int b = blockIdx.x;
    int idx = widx[b] % MM; if (idx < 0) idx += MM;
    const float ws = wstr[b];
    const float decay = decay_p[0];
    for (int d = tid; d < DD; d += blockDim.x) {
      float cw = content[b * DD + d] + ttab[(size_t)idx * DD + d];
      size_t off = (size_t)b * MM * DD + (size_t)idx * DD + d;
      float old = memory[off];
      memory[off] = old * (1.0f - ws) + cw * ws;
    }
    for (int m = tid; m < MM; m += blockDim.x) {
      float u = usage[b * MM + m] * decay;
      if (m == idx) u += ws;
      usage_out[b * MM + m] = u;
    }
    return;
  }

  // ---- qp part ----
  const int bid = blockIdx.x - 8;
  const int n0 = (bid & 15) * 32;
  const int r0 = (bid >> 4) * 64;
  const int wv = tid >> 6, lane = tid & 63;
  const int quad = lane >> 4, rr = lane & 15;
  const int wr = wv & 1, wc = wv >> 1;

  // B staging: 32 k-rows x 8 float4-cols = 256 chunks, 1/thread
  const int krow = tid >> 3, nc = tid & 7;

  f32x4 acc[2];
#pragma unroll
  for (int st = 0; st < 2; ++st)
#pragma unroll
    for (int c = 0; c < 4; ++c) acc[st][c] = 0.f;

  float4 wv4 = *(const float4*)(W + (size_t)krow * DD + n0 + nc * 4);
  {  // write buf 0 (transposed)
    float e[4] = {wv4.x, wv4.y, wv4.z, wv4.w};
#pragma unroll
    for (int i = 0; i < 4; ++i) {
      f16pair p = split2(e[i]);
      B1s[0][(nc * 4 + i) * QLSTR + krow] = p.h;
      B2s[0][(nc * 4 + i) * QLSTR + krow] = p.l;
    }
  }
  __syncthreads();

  for (int ks = 0; ks < 16; ++ks) {
    const int cur = ks & 1;
    if (ks < 15)
      wv4 = *(const float4*)(W + (size_t)((ks + 1) * 32 + krow) * DD + n0 + nc * 4);
    // A fragments (direct from global, fp32 -> split2)
    f16x8 a1[2], a2[2];
#pragma unroll
    for (int st = 0; st < 2; ++st) {
      int arow = r0 + wr * 32 + st * 16 + rr;
      cvt8(query + (size_t)arow * DD + ks * 32 + quad * 8, a1[st], a2[st]);
    }
    int col = wc * 16 + rr;
    f16x8 b1 = *(const f16x8*)&B1s[cur][col * QLSTR + quad * 8];
    f16x8 b2 = *(const f16x8*)&B2s[cur][col * QLSTR + quad * 8];
#pragma unroll
    for (int st = 0; st < 2; ++st) {
      acc[st] = __builtin_amdgcn_mfma_f32_16x16x32_f16(a1[st], b2, acc[st], 0, 0, 0);
      acc[st] = __builtin_amdgcn_mfma_f32_16x16x32_f16(a2[st], b1, acc[st], 0, 0, 0);
      acc[st] = __builtin_amdgcn_mfma_f32_16x16x32_f16(a1[st], b1, acc[st], 0, 0, 0);
    }
    if (ks < 15) {
      float e[4] = {wv4.x, wv4.y, wv4.z, wv4.w};
#pragma unroll
      for (int i = 0; i < 4; ++i) {
        f16pair p = split2(e[i]);
        B1s[cur ^ 1][(nc * 4 + i) * QLSTR + krow] = p.h;
        B2s[cur ^ 1][(nc * 4 + i) * QLSTR + krow] = p.l;
      }
    }
    __syncthreads();
  }
  // epilogue: C/D layout col=lane&15, row=quad*4+reg
#pragma unroll
  for (int st = 0; st < 2; ++st)
#pragma unroll
    for (int reg = 0; reg < 4; ++reg) {
      int row = r0 + wr * 32 + st * 16 + quad * 4 + reg;
      int col = n0 + wc * 16 + rr;
      f16pair p = split2(acc[st][reg]);
      q1[(size_t)row * DD + col] = p.h;
      q2[(size_t)row * DD + col] = p.l;
    }
}

// ---------------------------------------------------------------------------
// Kernel 2: scores via f16 2-way-split MFMA, 3 terms.
// Tile 128(S) x 64(M) x 32(K), grid 512 (2 blocks/CU), XCD-pinned batch.
// q fragments direct from global (L2-resident). memory staged in
// DOUBLE-BUFFERED LDS (fp32 -> split2 fused): load k+1 -> MFMA on buf[k]
// -> write buf[k+1] -> one barrier. Loads get the whole MFMA phase to land.
// ---------------------------------------------------------------------------
#define LSTR 40  // LDS row stride in f16 elems

__global__ __launch_bounds__(256, 2) void gemm_scores_mfma(
    const f16* __restrict__ q1_g, const f16* __restrict__ q2_g,
    const float* __restrict__ mem, float* __restrict__ sc_out) {
  __shared__ __align__(16) f16 m1_s[2][64 * LSTR];
  __shared__ __align__(16) f16 m2_s[2][64 * LSTR];
  const int tid = threadIdx.x;
  const int b = blockIdx.x & 7;                 // XCD-pinned batch
  const int j0 = (blockIdx.x >> 3) * 64;
  const int wv = tid >> 6, lane = tid & 63;
  const int quad = lane >> 4, rr = lane & 15;

  const f16* q1b = q1_g + (size_t)b * SS * DD;
  const f16* q2b = q2_g + (size_t)b * SS * DD;
  // m staging: 64 rows x 8 float4 = 512 chunks, 2/thread
  const int mrow = tid >> 3, mk = tid & 7;
  const float* mbase = mem + ((size_t)b * MM + j0) * DD;

  f32x4 acc[2][4];
#pragma unroll
  for (int i = 0; i < 2; ++i)
#pragma unroll
    for (int j = 0; j < 4; ++j)
#pragma unroll
      for (int c = 0; c < 4; ++c) acc[i][j][c] = 0.f;

  float4 mr0, mr1;
  f16x8 a1c[2], a2c[2], a1n[2], a2n[2];

  // prologue: k=0 loads + buf0 write
  mr0 = *(const float4*)(mbase + (size_t)mrow * DD + mk * 4);
  mr1 = *(const float4*)(mbase + (size_t)(mrow + 32) * DD + mk * 4);
#pragma unroll
  for (int st = 0; st < 2; ++st) {
    int srow = wv * 32 + st * 16 + rr;
    a1c[st] = *(const f16x8*)(q1b + (size_t)srow * DD + quad * 8);
    a2c[st] = *(const f16x8*)(q2b + (size_t)srow * DD + quad * 8);
  }
  split_store4(mr0, &m1_s[0][mrow * LSTR + mk * 4], &m2_s[0][mrow * LSTR + mk * 4]);
  split_store4(mr1, &m1_s[0][(mrow + 32) * LSTR + mk * 4], &m2_s[0][(mrow + 32) * LSTR + mk * 4]);
  __syncthreads();

  for (int ks = 0; ks < 16; ++ks) {
    const int cur = ks & 1;
    if (ks < 15) {  // prefetch k+1 (global); lands during the MFMA phase
      int k0 = (ks + 1) * 32;
      mr0 = *(const float4*)(mbase + (size_t)mrow * DD + k0 + mk * 4);
      mr1 = *(const float4*)(mbase + (size_t)(mrow + 32) * DD + k0 + mk * 4);
#pragma unroll
      for (int st = 0; st < 2; ++st) {
        int srow = wv * 32 + st * 16 + rr;
        a1n[st] = *(const f16x8*)(q1b + (size_t)srow * DD + k0 + quad * 8);
        a2n[st] = *(const f16x8*)(q2b + (size_t)srow * DD + k0 + quad * 8);
      }
    }
#pragma unroll
    for (int jt = 0; jt < 4; ++jt) {
      int brow = jt * 16 + rr;
      f16x8 b1 = *(const f16x8*)&m1_s[cur][brow * LSTR + quad * 8];
      f16x8 b2 = *(const f16x8*)&m2_s[cur][brow * LSTR + quad * 8];
#pragma unroll
      for (int st = 0; st < 2; ++st) {
        acc[st][jt] = __builtin_amdgcn_mfma_f32_16x16x32_f16(a1c[st], b2, acc[st][jt], 0, 0, 0);
        acc[st][jt] = __builtin_amdgcn_mfma_f32_16x16x32_f16(a2c[st], b1, acc[st][jt], 0, 0, 0);
        acc[st][jt] = __builtin_amdgcn_mfma_f32_16x16x32_f16(a1c[st], b1, acc[st][jt], 0, 0, 0);
      }
    }
    if (ks < 15) {  // write k+1 into the other buffer (no barrier before)
      const int nxt = cur ^ 1;
      split_store4(mr0, &m1_s[nxt][mrow * LSTR + mk * 4], &m2_s[nxt][mrow * LSTR + mk * 4]);
      split_store4(mr1, &m1_s[nxt][(mrow + 32) * LSTR + mk * 4], &m2_s[nxt][(mrow + 32) * LSTR + mk * 4]);
#pragma unroll
      for (int st = 0; st < 2; ++st) { a1c[st] = a1n[st]; a2c[st] = a2n[st]; }
    }
    __syncthreads();
  }
  // epilogue: C/D layout col=lane&15, row=quad*4+reg
  const float scl = 0.04419417382415922f;  // 1/sqrt(512)
  float* C = sc_out + (size_t)b * SS * MM;
#pragma unroll
  for (int st = 0; st < 2; ++st)
#pragma unroll
    for (int jt = 0; jt < 4; ++jt)
#pragma unroll
      for (int reg = 0; reg < 4; ++reg) {
        int srow = wv * 32 + st * 16 + quad * 4 + reg;
        int scol = j0 + jt * 16 + rr;
        C[(size_t)srow * MM + scol] = acc[st][jt][reg] * scl;
      }
}

// ---------------------------------------------------------------------------
// Kernel 3: per (b,s) row — mask, exact top-k threshold (radix select),
// softmax, dense attn write, retrieved gather. XCD-pinned: b = blockIdx&7
// so batch-b scores (written by XCD b) and its memory slice are L2-local.
// ---------------------------------------------------------------------------
__device__ __forceinline__ unsigned fkey(float f) {
  unsigned u = __float_as_uint(f);
  return (u & 0x80000000u) ? ~u : (u | 0x80000000u);
}
__device__ __forceinline__ float finv(unsigned u) {
  unsigned b = (u & 0x80000000u) ? (u & 0x7fffffffu) : ~u;
  return __uint_as_float(b);
}

__global__ __launch_bounds__(256) void select_kernel(
    const float* __restrict__ scores, const int* __restrict__ vmask,
    const int* __restrict__ widx, const int* __restrict__ topk,
    const float* __restrict__ memory, float* __restrict__ retrieved,
    float* __restrict__ attn) {
  __shared__ float sc[MM];
  __shared__ int kept[MM];
  __shared__ unsigned histw[4 * 256];
  __shared__ float red[256];
  __shared__ unsigned sh_pref;
  __shared__ int sh_k, sh_nkept;
  __shared__ float sh_zinv;

  const int tid = threadIdx.x;
  const int b = blockIdx.x & 7, s = blockIdx.x >> 3;  // XCD-pinned batch
  int wi = widx[b] % MM; if (wi < 0) wi += MM;
  const float4* srow4 = (const float4*)(scores + ((size_t)b * SS + s) * MM);
  const int4* vrow4 = (const int4*)(vmask + (size_t)b * MM);
  unsigned* hw = histw + (tid >> 6) * 256;

  if (tid == 0) { sh_pref = 0u; sh_nkept = 0; sh_k = topk[0]; }
  for (int i = tid; i < 1024; i += 256) histw[i] = 0u;
  __syncthreads();

  float lmax = -INFINITY;
  for (int m4 = tid; m4 < MM / 4; m4 += 256) {
    float4 v = srow4[m4];
    int4 mk = vrow4[m4];
    int mb = m4 * 4;
    if (!(mk.x || mb + 0 == wi)) v.x = -INFINITY;
    if (!(mk.y || mb + 1 == wi)) v.y = -INFINITY;
    if (!(mk.z || mb + 2 == wi)) v.z = -INFINITY;
    if (!(mk.w || mb + 3 == wi)) v.w = -INFINITY;
    ((float4*)sc)[m4] = v;
    lmax = fmaxf(lmax, fmaxf(fmaxf(v.x, v.y), fmaxf(v.z, v.w)));
    atomicAdd(&hw[fkey(v.x) >> 24], 1u);
    atomicAdd(&hw[fkey(v.y) >> 24], 1u);
    atomicAdd(&hw[fkey(v.z) >> 24], 1u);
    atomicAdd(&hw[fkey(v.w) >> 24], 1u);
  }
  red[tid] = lmax;
  __syncthreads();
#pragma unroll
  for (int off = 128; off > 0; off >>= 1) {
    if (tid < off) red[tid] = fmaxf(red[tid], red[tid + off]);
    __syncthreads();
  }
  const float maxv = red[0];

  for (int pass = 0; pass < 4; ++pass) {
    const int shift = 24 - pass * 8;
    if (pass > 0) {
      const unsigned pref = sh_pref;
      const unsigned hmask = 0xFFFFFFFFu << (shift + 8);
      for (int i = tid; i < 1024; i += 256) histw[i] = 0u;
      __syncthreads();
      for (int m = tid; m < MM; m += 256) {
        unsigned u = fkey(sc[m]);
        if ((u & hmask) == pref) atomicAdd(&hw[(u >> shift) & 0xFFu], 1u);
      }
      __syncthreads();
    }
    if (tid < 64) {
      const int l = tid;
      unsigned h0 = histw[l * 4 + 0] + histw[256 + l * 4 + 0] + histw[512 + l * 4 + 0] + histw[768 + l * 4 + 0];
      unsigned h1 = histw[l * 4 + 1] + histw[256 + l * 4 + 1] + histw[512 + l * 4 + 1] + histw[768 + l * 4 + 1];
      unsigned h2 = histw[l * 4 + 2] + histw[256 + l * 4 + 2] + histw[512 + l * 4 + 2] + histw[768 + l * 4 + 2];
      unsigned h3 = histw[l * 4 + 3] + histw[256 + l * 4 + 3] + histw[512 + l * 4 + 3] + histw[768 + l * 4 + 3];
      unsigned lsum = h0 + h1 + h2 + h3;
      unsigned g = lsum;
#pragma unroll
      for (int off = 1; off < 64; off <<= 1) {
        unsigned t = __shfl_down(g, off, 64);
        if (l + off < 64) g += t;
      }
      unsigned above = g - lsum;
      unsigned suf3 = h3 + above;
      unsigned suf2 = h2 + suf3;
      unsigned suf1 = h1 + suf2;
      unsigned suf0 = h0 + suf1;
      const unsigned kk = (unsigned)sh_k;
      const unsigned prefc = sh_pref;
      unsigned ge, geN;
      ge = suf0; geN = suf1;
      if (ge >= kk && geN < kk) { sh_pref = prefc | ((unsigned)(4 * l + 0) << shift); sh_k = (int)(kk - geN); }
      ge = suf1; geN = suf2;
      if (ge >= kk && geN < kk) { sh_pref = prefc | ((unsigned)(4 * l + 1) << shift); sh_k = (int)(kk - geN); }
      ge = suf2; geN = suf3;
      if (ge >= kk && geN < kk) { sh_pref = prefc | ((unsigned)(4 * l + 2) << shift); sh_k = (int)(kk - geN); }
      ge = suf3; geN = above;
      if (ge >= kk && geN < kk) { sh_pref = prefc | ((unsigned)(4 * l + 3) << shift); sh_k = (int)(kk - geN); }
    }
    __syncthreads();
  }
  const float thr = finv(sh_pref);

  float lz = 0.f;
  for (int m4 = tid; m4 < MM / 4; m4 += 256) {
    float4 v = ((float4*)sc)[m4];
    v.x = (v.x >= thr) ? __expf(v.x - maxv) : 0.f;
    v.y = (v.y >= thr) ? __expf(v.y - maxv) : 0.f;
    v.z = (v.z >= thr) ? __expf(v.z - maxv) : 0.f;
    v.w = (v.w >= thr) ? __expf(v.w - maxv) : 0.f;
    ((float4*)sc)[m4] = v;
    lz += v.x + v.y + v.z + v.w;
  }
  red[tid] = lz;
  __syncthreads();
#pragma unroll
  for (int off = 128; off > 0; off >>= 1) {
    if (tid < off) red[tid] += red[tid + off];
    __syncthreads();
  }
  if (tid == 0) sh_zinv = 1.0f / red[0];
  __syncthreads();
  const float zinv = sh_zinv;

  float4* arow4 = (float4*)(attn + ((size_t)b * SS + s) * MM);
  for (int m4 = tid; m4 < MM / 4; m4 += 256) {
    float4 p = ((float4*)sc)[m4];
    float4 o = make_float4(p.x * zinv, p.y * zinv, p.z * zinv, p.w * zinv);
    arow4[m4] = o;
    int mb = m4 * 4;
    if (p.x > 0.f) kept[atomicAdd(&sh_nkept, 1)] = mb + 0;
    if (p.y > 0.f) kept[atomicAdd(&sh_nkept, 1)] = mb + 1;
    if (p.z > 0.f) kept[atomicAdd(&sh_nkept, 1)] = mb + 2;
    if (p.w > 0.f) kept[atomicAdd(&sh_nkept, 1)] = mb + 3;
  }
  __syncthreads();
  const int nk = sh_nkept;

  float a0 = 0.f, a1 = 0.f;
  const float* mb_ = memory + (size_t)b * MM * DD;
  int i = 0;
  for (; i + 4 <= nk; i += 4) {
    int m0 = kept[i], m1 = kept[i + 1], m2 = kept[i + 2], m3 = kept[i + 3];
    float p0 = sc[m0], p1 = sc[m1], p2 = sc[m2], p3 = sc[m3];
    const float* r0 = mb_ + (size_t)m0 * DD;
    const float* r1 = mb_ + (size_t)m1 * DD;
    const float* r2 = mb_ + (size_t)m2 * DD;
    const float* r3 = mb_ + (size_t)m3 * DD;
    float v0a = r0[tid], v0b = r0[tid + 256];
    float v1a = r1[tid], v1b = r1[tid + 256];
    float v2a = r2[tid], v2b = r2[tid + 256];
    float v3a = r3[tid], v3b = r3[tid + 256];
    a0 += p0 * v0a + p1 * v1a + p2 * v2a + p3 * v3a;
    a1 += p0 * v0b + p1 * v1b + p2 * v2b + p3 * v3b;
  }
  for (; i < nk; ++i) {
    int m = kept[i];
    float p = sc[m];
    const float* mr = mb_ + (size_t)m * DD;
    a0 += p * mr[tid];
    a1 += p * mr[tid + 256];
  }
  float* rrow = retrieved + ((size_t)b * SS + s) * DD;
  rrow[tid] = a0 * zinv;
  rrow[tid + 256] = a1 * zinv;
}

// ---------------------------------------------------------------------------
extern "C" void kernel_launch(void* const* d_in, const int* in_sizes, int n_in,
                              void* d_out, int out_size, void* d_ws,
                              size_t ws_size, hipStream_t stream) {
  float* memory = (float*)d_in[0];
  const float* usage = (const float*)d_in[1];
  const float* content = (const float*)d_in[2];
  const float* wstr = (const float*)d_in[3];
  const float* query = (const float*)d_in[4];
  const float* W = (const float*)d_in[5];
  const float* ttab = (const float*)d_in[6];
  const float* decay = (const float*)d_in[7];
  const int* vmask = (const int*)d_in[8];
  const int* widx = (const int*)d_in[9];
  const int* topk = (const int*)d_in[10];

  float* out = (float*)d_out;
  float* retrieved = out;                              // B*S*D floats
  float* attn = out + (size_t)BB * SS * DD;            // B*S*M floats
  float* usage_out = attn + (size_t)BB * SS * MM;      // B*M floats

  const size_t qsz = (size_t)BB * SS * DD;             // elems per q array
  float* scores = (float*)d_ws;                        // 16 MB
  f16* q1;
  f16* q2;
  size_t need = (size_t)BB * SS * MM * 4 + 2 * qsz * 2;
  if (ws_size >= need) {
    q1 = (f16*)(scores + (size_t)BB * SS * MM);
    q2 = q1 + qsz;
  } else {
    q2 = (f16*)(attn + (size_t)BB * SS * MM) - qsz;
    q1 = q2 - qsz;
  }

  prep_kernel<<<8 + 256, 256, 0, stream>>>(memory, usage, content, wstr, ttab,
                                           decay, widx, usage_out, query, W,
                                           q1, q2);
  gemm_scores_mfma<<<dim3((MM / 64) * BB), 256, 0, stream>>>(q1, q2, memory,
                                                             scores);
  select_kernel<<<dim3(SS * BB), 256, 0, stream>>>(scores, vmask, widx, topk,
                                                   memory, retrieved, attn);
}

// Round 8
// 180.199 us; speedup vs baseline: 1.3713x; 1.0032x over previous
//
#include <hip/hip_runtime.h>
#include <hip/hip_bf16.h>
#include <math.h>

#define BB 8
#define MM 4096
#define DD 512
#define SS 128

typedef _Float16 f16;
typedef _Float16 f16x4 __attribute__((ext_vector_type(4)));
typedef _Float16 f16x8 __attribute__((ext_vector_type(8)));
typedef float f32x4 __attribute__((ext_vector_type(4)));

struct f16pair { f16 h; f16 l; };
// 2-way f16 split: x ~= h + l, residual <= 2^-22 |x|
__device__ __forceinline__ f16pair split2(float x) {
  f16pair p;
  p.h = (f16)x;
  p.l = (f16)(x - (float)p.h);
  return p;
}

// split a float4 into two f16x4 and store to LDS
__device__ __forceinline__ void split_store4(float4 v, f16* p1, f16* p2) {
  f16x4 h, l;
  f16pair p;
  p = split2(v.x); h[0] = p.h; l[0] = p.l;
  p = split2(v.y); h[1] = p.h; l[1] = p.l;
  p = split2(v.z); h[2] = p.h; l[2] = p.l;
  p = split2(v.w); h[3] = p.h; l[3] = p.l;
  *(f16x4*)p1 = h;
  *(f16x4*)p2 = l;
}

// split two float4 registers into two f16x8 fragments
__device__ __forceinline__ void cvt8r(float4 v0, float4 v1, f16x8& h, f16x8& l) {
  f16pair q;
  q = split2(v0.x); h[0] = q.h; l[0] = q.l;
  q = split2(v0.y); h[1] = q.h; l[1] = q.l;
  q = split2(v0.z); h[2] = q.h; l[2] = q.l;
  q = split2(v0.w); h[3] = q.h; l[3] = q.l;
  q = split2(v1.x); h[4] = q.h; l[4] = q.l;
  q = split2(v1.y); h[5] = q.h; l[5] = q.l;
  q = split2(v1.z); h[6] = q.h; l[6] = q.l;
  q = split2(v1.w); h[7] = q.h; l[7] = q.l;
}

// ---------------------------------------------------------------------------
// Kernel 1 (fused): blocks 0..7 = memory row write + usage decay;
// blocks 8..263 = qp = query @ W via f16 3-term MFMA (64R x 32N x 32K).
// A-fragments register-prefetched from global (k+1 loads issued before the
// MFMA phase); W tile transposed+split into double-buffered LDS.
// ---------------------------------------------------------------------------
#define QLSTR 40  // LDS row stride in f16 elems

__global__ __launch_bounds__(256) void prep_kernel(
    float* __restrict__ memory, const float* __restrict__ usage,
    const float* __restrict__ content, const float* __restrict__ wstr,
    const float* __restrict__ ttab, const float* __restrict__ decay_p,
    const int* __restrict__ widx, float* __restrict__ usage_out,
    const float* __restrict__ query, const float* __restrict__ W,
    f16* __restrict__ q1, f16* __restrict__ q2) {
  __shared__ __align__(16) f16 B1s[2][32 * QLSTR];
  __shared__ __align__(16) f16 B2s[2][32 * QLSTR];
  const int tid = threadIdx.x;

  if (blockIdx.x < 8) {  // ---- update part ----
    const int b = blockIdx.x;
    int idx = widx[b] % MM; if (idx < 0) idx += MM;
    const float ws = wstr[b];
    const float decay = decay_p[0];
    for (int d = tid; d < DD; d += blockDim.x) {
      float cw = content[b * DD + d] + ttab[(size_t)idx * DD + d];
      size_t off = (size_t)b * MM * DD + (size_t)idx * DD + d;
      float old = memory[off];
      memory[off] = old * (1.0f - ws) + cw * ws;
    }
    for (int m = tid; m < MM; m += blockDim.x) {
      float u = usage[b * MM + m] * decay;
      if (m == idx) u += ws;
      usage_out[b * MM + m] = u;
    }
    return;
  }

  // ---- qp part ----
  const int bid = blockIdx.x - 8;
  const int n0 = (bid & 15) * 32;
  const int r0 = (bid >> 4) * 64;
  const int wv = tid >> 6, lane = tid & 63;
  const int quad = lane >> 4, rr = lane & 15;
  const int wr = wv & 1, wc = wv >> 1;

  // B staging: 32 k-rows x 8 float4-cols = 256 chunks, 1/thread
  const int krow = tid >> 3, nc = tid & 7;

  f32x4 acc[2];
#pragma unroll
  for (int st = 0; st < 2; ++st)
#pragma unroll
    for (int c = 0; c < 4; ++c) acc[st][c] = 0.f;

  float4 wv4 = *(const float4*)(W + (size_t)krow * DD + n0 + nc * 4);
  float4 aq[2][2], an[2][2];
#pragma unroll
  for (int st = 0; st < 2; ++st) {
    int arow = r0 + wr * 32 + st * 16 + rr;
    aq[st][0] = *(const float4*)(query + (size_t)arow * DD + quad * 8);
    aq[st][1] = *(const float4*)(query + (size_t)arow * DD + quad * 8 + 4);
  }
  {  // write W buf 0 (transposed)
    float e[4] = {wv4.x, wv4.y, wv4.z, wv4.w};
#pragma unroll
    for (int i = 0; i < 4; ++i) {
      f16pair p = split2(e[i]);
      B1s[0][(nc * 4 + i) * QLSTR + krow] = p.h;
      B2s[0][(nc * 4 + i) * QLSTR + krow] = p.l;
    }
  }
  __syncthreads();

  for (int ks = 0; ks < 16; ++ks) {
    const int cur = ks & 1;
    if (ks < 15) {  // prefetch k+1 (W + A) before the MFMA phase
      int k0 = (ks + 1) * 32;
      wv4 = *(const float4*)(W + (size_t)(k0 + krow) * DD + n0 + nc * 4);
#pragma unroll
      for (int st = 0; st < 2; ++st) {
        int arow = r0 + wr * 32 + st * 16 + rr;
        an[st][0] = *(const float4*)(query + (size_t)arow * DD + k0 + quad * 8);
        an[st][1] = *(const float4*)(query + (size_t)arow * DD + k0 + quad * 8 + 4);
      }
    }
    f16x8 a1[2], a2[2];
#pragma unroll
    for (int st = 0; st < 2; ++st) cvt8r(aq[st][0], aq[st][1], a1[st], a2[st]);
    int col = wc * 16 + rr;
    f16x8 b1 = *(const f16x8*)&B1s[cur][col * QLSTR + quad * 8];
    f16x8 b2 = *(const f16x8*)&B2s[cur][col * QLSTR + quad * 8];
#pragma unroll
    for (int st = 0; st < 2; ++st) {
      acc[st] = __builtin_amdgcn_mfma_f32_16x16x32_f16(a1[st], b2, acc[st], 0, 0, 0);
      acc[st] = __builtin_amdgcn_mfma_f32_16x16x32_f16(a2[st], b1, acc[st], 0, 0, 0);
      acc[st] = __builtin_amdgcn_mfma_f32_16x16x32_f16(a1[st], b1, acc[st], 0, 0, 0);
    }
    if (ks < 15) {
      float e[4] = {wv4.x, wv4.y, wv4.z, wv4.w};
#pragma unroll
      for (int i = 0; i < 4; ++i) {
        f16pair p = split2(e[i]);
        B1s[cur ^ 1][(nc * 4 + i) * QLSTR + krow] = p.h;
        B2s[cur ^ 1][(nc * 4 + i) * QLSTR + krow] = p.l;
      }
#pragma unroll
      for (int st = 0; st < 2; ++st) { aq[st][0] = an[st][0]; aq[st][1] = an[st][1]; }
    }
    __syncthreads();
  }
  // epilogue: C/D layout col=lane&15, row=quad*4+reg
#pragma unroll
  for (int st = 0; st < 2; ++st)
#pragma unroll
    for (int reg = 0; reg < 4; ++reg) {
      int row = r0 + wr * 32 + st * 16 + quad * 4 + reg;
      int col = n0 + wc * 16 + rr;
      f16pair p = split2(acc[st][reg]);
      q1[(size_t)row * DD + col] = p.h;
      q2[(size_t)row * DD + col] = p.l;
    }
}

// ---------------------------------------------------------------------------
// Kernel 2: scores via f16 2-way-split MFMA, 3 terms.
// Tile 128(S) x 64(M) x 32(K), grid 512, XCD-pinned batch, double-buffered
// LDS for memory (fp32 -> split2 fused), q direct from global (L2).
// ---------------------------------------------------------------------------
#define LSTR 40  // LDS row stride in f16 elems

__global__ __launch_bounds__(256, 2) void gemm_scores_mfma(
    const f16* __restrict__ q1_g, const f16* __restrict__ q2_g,
    const float* __restrict__ mem, float* __restrict__ sc_out) {
  __shared__ __align__(16) f16 m1_s[2][64 * LSTR];
  __shared__ __align__(16) f16 m2_s[2][64 * LSTR];
  const int tid = threadIdx.x;
  const int b = blockIdx.x & 7;                 // XCD-pinned batch
  const int j0 = (blockIdx.x >> 3) * 64;
  const int wv = tid >> 6, lane = tid & 63;
  const int quad = lane >> 4, rr = lane & 15;

  const f16* q1b = q1_g + (size_t)b * SS * DD;
  const f16* q2b = q2_g + (size_t)b * SS * DD;
  const int mrow = tid >> 3, mk = tid & 7;
  const float* mbase = mem + ((size_t)b * MM + j0) * DD;

  f32x4 acc[2][4];
#pragma unroll
  for (int i = 0; i < 2; ++i)
#pragma unroll
    for (int j = 0; j < 4; ++j)
#pragma unroll
      for (int c = 0; c < 4; ++c) acc[i][j][c] = 0.f;

  float4 mr0, mr1;
  f16x8 a1c[2], a2c[2], a1n[2], a2n[2];

  mr0 = *(const float4*)(mbase + (size_t)mrow * DD + mk * 4);
  mr1 = *(const float4*)(mbase + (size_t)(mrow + 32) * DD + mk * 4);
#pragma unroll
  for (int st = 0; st < 2; ++st) {
    int srow = wv * 32 + st * 16 + rr;
    a1c[st] = *(const f16x8*)(q1b + (size_t)srow * DD + quad * 8);
    a2c[st] = *(const f16x8*)(q2b + (size_t)srow * DD + quad * 8);
  }
  split_store4(mr0, &m1_s[0][mrow * LSTR + mk * 4], &m2_s[0][mrow * LSTR + mk * 4]);
  split_store4(mr1, &m1_s[0][(mrow + 32) * LSTR + mk * 4], &m2_s[0][(mrow + 32) * LSTR + mk * 4]);
  __syncthreads();

  for (int ks = 0; ks < 16; ++ks) {
    const int cur = ks & 1;
    if (ks < 15) {
      int k0 = (ks + 1) * 32;
      mr0 = *(const float4*)(mbase + (size_t)mrow * DD + k0 + mk * 4);
      mr1 = *(const float4*)(mbase + (size_t)(mrow + 32) * DD + k0 + mk * 4);
#pragma unroll
      for (int st = 0; st < 2; ++st) {
        int srow = wv * 32 + st * 16 + rr;
        a1n[st] = *(const f16x8*)(q1b + (size_t)srow * DD + k0 + quad * 8);
        a2n[st] = *(const f16x8*)(q2b + (size_t)srow * DD + k0 + quad * 8);
      }
    }
#pragma unroll
    for (int jt = 0; jt < 4; ++jt) {
      int brow = jt * 16 + rr;
      f16x8 b1 = *(const f16x8*)&m1_s[cur][brow * LSTR + quad * 8];
      f16x8 b2 = *(const f16x8*)&m2_s[cur][brow * LSTR + quad * 8];
#pragma unroll
      for (int st = 0; st < 2; ++st) {
        acc[st][jt] = __builtin_amdgcn_mfma_f32_16x16x32_f16(a1c[st], b2, acc[st][jt], 0, 0, 0);
        acc[st][jt] = __builtin_amdgcn_mfma_f32_16x16x32_f16(a2c[st], b1, acc[st][jt], 0, 0, 0);
        acc[st][jt] = __builtin_amdgcn_mfma_f32_16x16x32_f16(a1c[st], b1, acc[st][jt], 0, 0, 0);
      }
    }
    if (ks < 15) {
      const int nxt = cur ^ 1;
      split_store4(mr0, &m1_s[nxt][mrow * LSTR + mk * 4], &m2_s[nxt][mrow * LSTR + mk * 4]);
      split_store4(mr1, &m1_s[nxt][(mrow + 32) * LSTR + mk * 4], &m2_s[nxt][(mrow + 32) * LSTR + mk * 4]);
#pragma unroll
      for (int st = 0; st < 2; ++st) { a1c[st] = a1n[st]; a2c[st] = a2n[st]; }
    }
    __syncthreads();
  }
  const float scl = 0.04419417382415922f;  // 1/sqrt(512)
  float* C = sc_out + (size_t)b * SS * MM;
#pragma unroll
  for (int st = 0; st < 2; ++st)
#pragma unroll
    for (int jt = 0; jt < 4; ++jt)
#pragma unroll
      for (int reg = 0; reg < 4; ++reg) {
        int srow = wv * 32 + st * 16 + quad * 4 + reg;
        int scol = j0 + jt * 16 + rr;
        C[(size_t)srow * MM + scol] = acc[st][jt][reg] * scl;
      }
}

// ---------------------------------------------------------------------------
// Kernel 3: per (b,s) row — mask, exact top-k threshold (radix select),
// softmax, dense attn write, retrieved gather. XCD-pinned (b = blockIdx&7).
// LDS ~21 KB (7 blocks/CU); wave-shuffle reductions; float2 gather.
// ---------------------------------------------------------------------------
__device__ __forceinline__ unsigned fkey(float f) {
  unsigned u = __float_as_uint(f);
  return (u & 0x80000000u) ? ~u : (u | 0x80000000u);
}
__device__ __forceinline__ float finv(unsigned u) {
  unsigned b = (u & 0x80000000u) ? (u & 0x7fffffffu) : ~u;
  return __uint_as_float(b);
}

#define NKEPT 128  // top-k=64 + tie margin (ties beyond 64 need bit-equal fp32)

__global__ __launch_bounds__(256) void select_kernel(
    const float* __restrict__ scores, const int* __restrict__ vmask,
    const int* __restrict__ widx, const int* __restrict__ topk,
    const float* __restrict__ memory, float* __restrict__ retrieved,
    float* __restrict__ attn) {
  __shared__ float sc[MM];           // 16 KB
  __shared__ int kept[NKEPT];        // 512 B
  __shared__ unsigned histw[4 * 256];// 4 KB (per-wave histograms)
  __shared__ float red4[4];
  __shared__ unsigned sh_pref;
  __shared__ int sh_k, sh_nkept;
  __shared__ float sh_zinv;

  const int tid = threadIdx.x;
  const int b = blockIdx.x & 7, s = blockIdx.x >> 3;  // XCD-pinned batch
  const int lane = tid & 63, wv = tid >> 6;
  int wi = widx[b] % MM; if (wi < 0) wi += MM;
  const float4* srow4 = (const float4*)(scores + ((size_t)b * SS + s) * MM);
  const int4* vrow4 = (const int4*)(vmask + (size_t)b * MM);
  unsigned* hw = histw + wv * 256;

  if (tid == 0) { sh_pref = 0u; sh_nkept = 0; sh_k = topk[0]; }
  for (int i = tid; i < 1024; i += 256) histw[i] = 0u;
  __syncthreads();

  // load + mask + row max + fused radix pass-0 histogram
  float lmax = -INFINITY;
  for (int m4 = tid; m4 < MM / 4; m4 += 256) {
    float4 v = srow4[m4];
    int4 mk = vrow4[m4];
    int mb = m4 * 4;
    if (!(mk.x || mb + 0 == wi)) v.x = -INFINITY;
    if (!(mk.y || mb + 1 == wi)) v.y = -INFINITY;
    if (!(mk.z || mb + 2 == wi)) v.z = -INFINITY;
    if (!(mk.w || mb + 3 == wi)) v.w = -INFINITY;
    ((float4*)sc)[m4] = v;
    lmax = fmaxf(lmax, fmaxf(fmaxf(v.x, v.y), fmaxf(v.z, v.w)));
    atomicAdd(&hw[fkey(v.x) >> 24], 1u);
    atomicAdd(&hw[fkey(v.y) >> 24], 1u);
    atomicAdd(&hw[fkey(v.z) >> 24], 1u);
    atomicAdd(&hw[fkey(v.w) >> 24], 1u);
  }
#pragma unroll
  for (int off = 32; off > 0; off >>= 1)
    lmax = fmaxf(lmax, __shfl_xor(lmax, off));
  if (lane == 0) red4[wv] = lmax;
  __syncthreads();
  const float maxv = fmaxf(fmaxf(red4[0], red4[1]), fmaxf(red4[2], red4[3]));

  // radix select: 4 passes over 8-bit digits; pass-0 histogram already built
  for (int pass = 0; pass < 4; ++pass) {
    const int shift = 24 - pass * 8;
    if (pass > 0) {
      const unsigned pref = sh_pref;
      const unsigned hmask = 0xFFFFFFFFu << (shift + 8);
      for (int i = tid; i < 1024; i += 256) histw[i] = 0u;
      __syncthreads();
      for (int m = tid; m < MM; m += 256) {
        unsigned u = fkey(sc[m]);
        if ((u & hmask) == pref) atomicAdd(&hw[(u >> shift) & 0xFFu], 1u);
      }
      __syncthreads();
    }
    if (tid < 64) {
      const int l = tid;
      unsigned h0 = histw[l * 4 + 0] + histw[256 + l * 4 + 0] + histw[512 + l * 4 + 0] + histw[768 + l * 4 + 0];
      unsigned h1 = histw[l * 4 + 1] + histw[256 + l * 4 + 1] + histw[512 + l * 4 + 1] + histw[768 + l * 4 + 1];
      unsigned h2 = histw[l * 4 + 2] + histw[256 + l * 4 + 2] + histw[512 + l * 4 + 2] + histw[768 + l * 4 + 2];
      unsigned h3 = histw[l * 4 + 3] + histw[256 + l * 4 + 3] + histw[512 + l * 4 + 3] + histw[768 + l * 4 + 3];
      unsigned lsum = h0 + h1 + h2 + h3;
      unsigned g = lsum;  // inclusive suffix scan across lanes
#pragma unroll
      for (int off = 1; off < 64; off <<= 1) {
        unsigned t = __shfl_down(g, off, 64);
        if (l + off < 64) g += t;
      }
      unsigned above = g - lsum;
      unsigned suf3 = h3 + above;
      unsigned suf2 = h2 + suf3;
      unsigned suf1 = h1 + suf2;
      unsigned suf0 = h0 + suf1;
      const unsigned kk = (unsigned)sh_k;
      const unsigned prefc = sh_pref;
      unsigned ge, geN;
      ge = suf0; geN = suf1;
      if (ge >= kk && geN < kk) { sh_pref = prefc | ((unsigned)(4 * l + 0) << shift); sh_k = (int)(kk - geN); }
      ge = suf1; geN = suf2;
      if (ge >= kk && geN < kk) { sh_pref = prefc | ((unsigned)(4 * l + 1) << shift); sh_k = (int)(kk - geN); }
      ge = suf2; geN = suf3;
      if (ge >= kk && geN < kk) { sh_pref = prefc | ((unsigned)(4 * l + 2) << shift); sh_k = (int)(kk - geN); }
      ge = suf3; geN = above;
      if (ge >= kk && geN < kk) { sh_pref = prefc | ((unsigned)(4 * l + 3) << shift); sh_k = (int)(kk - geN); }
    }
    __syncthreads();
  }
  const float thr = finv(sh_pref);

  // probs + Z (wave-shuffle reduction)
  float lz = 0.f;
  for (int m4 = tid; m4 < MM / 4; m4 += 256) {
    float4 v = ((float4*)sc)[m4];
    v.x = (v.x >= thr) ? __expf(v.x - maxv) : 0.f;
    v.y = (v.y >= thr) ? __expf(v.y - maxv) : 0.f;
    v.z = (v.z >= thr) ? __expf(v.z - maxv) : 0.f;
    v.w = (v.w >= thr) ? __expf(v.w - maxv) : 0.f;
    ((float4*)sc)[m4] = v;
    lz += v.x + v.y + v.z + v.w;
  }
#pragma unroll
  for (int off = 32; off > 0; off >>= 1) lz += __shfl_xor(lz, off);
  if (lane == 0) red4[wv] = lz;
  __syncthreads();
  if (tid == 0) sh_zinv = 1.0f / (red4[0] + red4[1] + red4[2] + red4[3]);
  __syncthreads();
  const float zinv = sh_zinv;

  // dense attn write + kept list
  float4* arow4 = (float4*)(attn + ((size_t)b * SS + s) * MM);
  for (int m4 = tid; m4 < MM / 4; m4 += 256) {
    float4 p = ((float4*)sc)[m4];
    float4 o = make_float4(p.x * zinv, p.y * zinv, p.z * zinv, p.w * zinv);
    arow4[m4] = o;
    int mb = m4 * 4;
    if (p.x > 0.f) { int q = atomicAdd(&sh_nkept, 1); if (q < NKEPT) kept[q] = mb + 0; }
    if (p.y > 0.f) { int q = atomicAdd(&sh_nkept, 1); if (q < NKEPT) kept[q] = mb + 1; }
    if (p.z > 0.f) { int q = atomicAdd(&sh_nkept, 1); if (q < NKEPT) kept[q] = mb + 2; }
    if (p.w > 0.f) { int q = atomicAdd(&sh_nkept, 1); if (q < NKEPT) kept[q] = mb + 3; }
  }
  __syncthreads();
  const int nk = min(sh_nkept, NKEPT);

  // retrieved[b][s][:] = sum_kept p * memory_row (float2 lanes, unrolled x4)
  float ax = 0.f, ay = 0.f;
  const float* mb_ = memory + (size_t)b * MM * DD;
  int i = 0;
  for (; i + 4 <= nk; i += 4) {
    int m0 = kept[i], m1 = kept[i + 1], m2 = kept[i + 2], m3 = kept[i + 3];
    float p0 = sc[m0], p1 = sc[m1], p2 = sc[m2], p3 = sc[m3];
    float2 v0 = ((const float2*)(mb_ + (size_t)m0 * DD))[tid];
    float2 v1 = ((const float2*)(mb_ + (size_t)m1 * DD))[tid];
    float2 v2 = ((const float2*)(mb_ + (size_t)m2 * DD))[tid];
    float2 v3 = ((const float2*)(mb_ + (size_t)m3 * DD))[tid];
    ax += p0 * v0.x + p1 * v1.x + p2 * v2.x + p3 * v3.x;
    ay += p0 * v0.y + p1 * v1.y + p2 * v2.y + p3 * v3.y;
  }
  for (; i < nk; ++i) {
    int m = kept[i];
    float p = sc[m];
    float2 v = ((const float2*)(mb_ + (size_t)m * DD))[tid];
    ax += p * v.x;
    ay += p * v.y;
  }
  float2* rrow = (float2*)(retrieved + ((size_t)b * SS + s) * DD);
  rrow[tid] = make_float2(ax * zinv, ay * zinv);
}

// ---------------------------------------------------------------------------
extern "C" void kernel_launch(void* const* d_in, const int* in_sizes, int n_in,
                              void* d_out, int out_size, void* d_ws,
                              size_t ws_size, hipStream_t stream) {
  float* memory = (float*)d_in[0];
  const float* usage = (const float*)d_in[1];
  const float* content = (const float*)d_in[2];
  const float* wstr = (const float*)d_in[3];
  const float* query = (const float*)d_in[4];
  const float* W = (const float*)d_in[5];
  const float* ttab = (const float*)d_in[6];
  const float* decay = (const float*)d_in[7];
  const int* vmask = (const int*)d_in[8];
  const int* widx = (const int*)d_in[9];
  const int* topk = (const int*)d_in[10];

  float* out = (float*)d_out;
  float* retrieved = out;                              // B*S*D floats
  float* attn = out + (size_t)BB * SS * DD;            // B*S*M floats
  float* usage_out = attn + (size_t)BB * SS * MM;      // B*M floats

  const size_t qsz = (size_t)BB * SS * DD;             // elems per q array
  float* scores = (float*)d_ws;                        // 16 MB
  f16* q1;
  f16* q2;
  size_t need = (size_t)BB * SS * MM * 4 + 2 * qsz * 2;
  if (ws_size >= need) {
    q1 = (f16*)(scores + (size_t)BB * SS * MM);
    q2 = q1 + qsz;
  } else {
    q2 = (f16*)(attn + (size_t)BB * SS * MM) - qsz;
    q1 = q2 - qsz;
  }

  prep_kernel<<<8 + 256, 256, 0, stream>>>(memory, usage, content, wstr, ttab,
                                           decay, widx, usage_out, query, W,
                                           q1, q2);
  gemm_scores_mfma<<<dim3((MM / 64) * BB), 256, 0, stream>>>(q1, q2, memory,
                                                             scores);
  select_kernel<<<dim3(SS * BB), 256, 0, stream>>>(scores, vmask, widx, topk,
                                                   memory, retrieved, attn);
}

// Round 9
// 173.277 us; speedup vs baseline: 1.4261x; 1.0399x over previous
//
#include <hip/hip_runtime.h>
#include <hip/hip_bf16.h>
#include <math.h>

#define BB 8
#define MM 4096
#define DD 512
#define SS 128

typedef _Float16 f16;
typedef _Float16 f16x4 __attribute__((ext_vector_type(4)));
typedef _Float16 f16x8 __attribute__((ext_vector_type(8)));
typedef float f32x4 __attribute__((ext_vector_type(4)));

struct f16pair { f16 h; f16 l; };
// 2-way f16 split: x ~= h + l, residual <= 2^-22 |x|
__device__ __forceinline__ f16pair split2(float x) {
  f16pair p;
  p.h = (f16)x;
  p.l = (f16)(x - (float)p.h);
  return p;
}

// split a float4 into two f16x4 and store to LDS
__device__ __forceinline__ void split_store4(float4 v, f16* p1, f16* p2) {
  f16x4 h, l;
  f16pair p;
  p = split2(v.x); h[0] = p.h; l[0] = p.l;
  p = split2(v.y); h[1] = p.h; l[1] = p.l;
  p = split2(v.z); h[2] = p.h; l[2] = p.l;
  p = split2(v.w); h[3] = p.h; l[3] = p.l;
  *(f16x4*)p1 = h;
  *(f16x4*)p2 = l;
}

// split two float4 registers into two f16x8 fragments
__device__ __forceinline__ void cvt8r(float4 v0, float4 v1, f16x8& h, f16x8& l) {
  f16pair q;
  q = split2(v0.x); h[0] = q.h; l[0] = q.l;
  q = split2(v0.y); h[1] = q.h; l[1] = q.l;
  q = split2(v0.z); h[2] = q.h; l[2] = q.l;
  q = split2(v0.w); h[3] = q.h; l[3] = q.l;
  q = split2(v1.x); h[4] = q.h; l[4] = q.l;
  q = split2(v1.y); h[5] = q.h; l[5] = q.l;
  q = split2(v1.z); h[6] = q.h; l[6] = q.l;
  q = split2(v1.w); h[7] = q.h; l[7] = q.l;
}

// ---------------------------------------------------------------------------
// Kernel 1 (fused): blocks 0..7 = memory row write + usage decay;
// blocks 8..519 = qp = query @ W via f16 3-term MFMA (32R x 32N x 32K,
// one 16x16 tile per wave, 512 blocks = 2/CU). A register-prefetched from
// global; W transposed+split into double-buffered LDS.
// ---------------------------------------------------------------------------
#define QLSTR 40  // LDS row stride in f16 elems

__global__ __launch_bounds__(256) void prep_kernel(
    float* __restrict__ memory, const float* __restrict__ usage,
    const float* __restrict__ content, const float* __restrict__ wstr,
    const float* __restrict__ ttab, const float* __restrict__ decay_p,
    const int* __restrict__ widx, float* __restrict__ usage_out,
    const float* __restrict__ query, const float* __restrict__ W,
    f16* __restrict__ q1, f16* __restrict__ q2) {
  __shared__ __align__(16) f16 B1s[2][32 * QLSTR];
  __shared__ __align__(16) f16 B2s[2][32 * QLSTR];
  const int tid = threadIdx.x;

  if (blockIdx.x < 8) {  // ---- update part ----
    const int b = blockIdx.x;
    int idx = widx[b] % MM; if (idx < 0) idx += MM;
    const float ws = wstr[b];
    const float decay = decay_p[0];
    for (int d = tid; d < DD; d += blockDim.x) {
      float cw = content[b * DD + d] + ttab[(size_t)idx * DD + d];
      size_t off = (size_t)b * MM * DD + (size_t)idx * DD + d;
      float old = memory[off];
      memory[off] = old * (1.0f - ws) + cw * ws;
    }
    for (int m = tid; m < MM; m += blockDim.x) {
      float u = usage[b * MM + m] * decay;
      if (m == idx) u += ws;
      usage_out[b * MM + m] = u;
    }
    return;
  }

  // ---- qp part: 32R x 32N, one 16x16 tile per wave ----
  const int bid = blockIdx.x - 8;
  const int n0 = (bid & 15) * 32;
  const int r0 = (bid >> 4) * 32;
  const int wv = tid >> 6, lane = tid & 63;
  const int quad = lane >> 4, rr = lane & 15;
  const int wr = wv & 1, wc = wv >> 1;

  // B staging: 32 k-rows x 8 float4-cols = 256 chunks, 1/thread
  const int krow = tid >> 3, nc = tid & 7;

  f32x4 acc;
#pragma unroll
  for (int c = 0; c < 4; ++c) acc[c] = 0.f;

  const int arow = r0 + wr * 16 + rr;
  float4 wv4 = *(const float4*)(W + (size_t)krow * DD + n0 + nc * 4);
  float4 aq0 = *(const float4*)(query + (size_t)arow * DD + quad * 8);
  float4 aq1 = *(const float4*)(query + (size_t)arow * DD + quad * 8 + 4);
  float4 an0, an1;
  {  // write W buf 0 (transposed)
    float e[4] = {wv4.x, wv4.y, wv4.z, wv4.w};
#pragma unroll
    for (int i = 0; i < 4; ++i) {
      f16pair p = split2(e[i]);
      B1s[0][(nc * 4 + i) * QLSTR + krow] = p.h;
      B2s[0][(nc * 4 + i) * QLSTR + krow] = p.l;
    }
  }
  __syncthreads();

  for (int ks = 0; ks < 16; ++ks) {
    const int cur = ks & 1;
    if (ks < 15) {  // prefetch k+1 (W + A)
      int k0 = (ks + 1) * 32;
      wv4 = *(const float4*)(W + (size_t)(k0 + krow) * DD + n0 + nc * 4);
      an0 = *(const float4*)(query + (size_t)arow * DD + k0 + quad * 8);
      an1 = *(const float4*)(query + (size_t)arow * DD + k0 + quad * 8 + 4);
    }
    f16x8 a1, a2;
    cvt8r(aq0, aq1, a1, a2);
    int col = wc * 16 + rr;
    f16x8 b1 = *(const f16x8*)&B1s[cur][col * QLSTR + quad * 8];
    f16x8 b2 = *(const f16x8*)&B2s[cur][col * QLSTR + quad * 8];
    acc = __builtin_amdgcn_mfma_f32_16x16x32_f16(a1, b2, acc, 0, 0, 0);
    acc = __builtin_amdgcn_mfma_f32_16x16x32_f16(a2, b1, acc, 0, 0, 0);
    acc = __builtin_amdgcn_mfma_f32_16x16x32_f16(a1, b1, acc, 0, 0, 0);
    if (ks < 15) {
      float e[4] = {wv4.x, wv4.y, wv4.z, wv4.w};
#pragma unroll
      for (int i = 0; i < 4; ++i) {
        f16pair p = split2(e[i]);
        B1s[cur ^ 1][(nc * 4 + i) * QLSTR + krow] = p.h;
        B2s[cur ^ 1][(nc * 4 + i) * QLSTR + krow] = p.l;
      }
      aq0 = an0; aq1 = an1;
    }
    __syncthreads();
  }
  // epilogue: C/D layout col=lane&15, row=quad*4+reg
#pragma unroll
  for (int reg = 0; reg < 4; ++reg) {
    int row = r0 + wr * 16 + quad * 4 + reg;
    int col = n0 + wc * 16 + rr;
    f16pair p = split2(acc[reg]);
    q1[(size_t)row * DD + col] = p.h;
    q2[(size_t)row * DD + col] = p.l;
  }
}

// ---------------------------------------------------------------------------
// Kernel 2: scores via f16 2-way-split MFMA, 3 terms.
// Tile 128(S) x 64(M) x 32(K), grid 512, XCD-pinned batch, double-buffered
// LDS for memory (fp32 -> split2 fused), q direct from global (L2).
// ---------------------------------------------------------------------------
#define LSTR 40  // LDS row stride in f16 elems

__global__ __launch_bounds__(256, 2) void gemm_scores_mfma(
    const f16* __restrict__ q1_g, const f16* __restrict__ q2_g,
    const float* __restrict__ mem, float* __restrict__ sc_out) {
  __shared__ __align__(16) f16 m1_s[2][64 * LSTR];
  __shared__ __align__(16) f16 m2_s[2][64 * LSTR];
  const int tid = threadIdx.x;
  const int b = blockIdx.x & 7;                 // XCD-pinned batch
  const int j0 = (blockIdx.x >> 3) * 64;
  const int wv = tid >> 6, lane = tid & 63;
  const int quad = lane >> 4, rr = lane & 15;

  const f16* q1b = q1_g + (size_t)b * SS * DD;
  const f16* q2b = q2_g + (size_t)b * SS * DD;
  const int mrow = tid >> 3, mk = tid & 7;
  const float* mbase = mem + ((size_t)b * MM + j0) * DD;

  f32x4 acc[2][4];
#pragma unroll
  for (int i = 0; i < 2; ++i)
#pragma unroll
    for (int j = 0; j < 4; ++j)
#pragma unroll
      for (int c = 0; c < 4; ++c) acc[i][j][c] = 0.f;

  float4 mr0, mr1;
  f16x8 a1c[2], a2c[2], a1n[2], a2n[2];

  mr0 = *(const float4*)(mbase + (size_t)mrow * DD + mk * 4);
  mr1 = *(const float4*)(mbase + (size_t)(mrow + 32) * DD + mk * 4);
#pragma unroll
  for (int st = 0; st < 2; ++st) {
    int srow = wv * 32 + st * 16 + rr;
    a1c[st] = *(const f16x8*)(q1b + (size_t)srow * DD + quad * 8);
    a2c[st] = *(const f16x8*)(q2b + (size_t)srow * DD + quad * 8);
  }
  split_store4(mr0, &m1_s[0][mrow * LSTR + mk * 4], &m2_s[0][mrow * LSTR + mk * 4]);
  split_store4(mr1, &m1_s[0][(mrow + 32) * LSTR + mk * 4], &m2_s[0][(mrow + 32) * LSTR + mk * 4]);
  __syncthreads();

  for (int ks = 0; ks < 16; ++ks) {
    const int cur = ks & 1;
    if (ks < 15) {
      int k0 = (ks + 1) * 32;
      mr0 = *(const float4*)(mbase + (size_t)mrow * DD + k0 + mk * 4);
      mr1 = *(const float4*)(mbase + (size_t)(mrow + 32) * DD + k0 + mk * 4);
#pragma unroll
      for (int st = 0; st < 2; ++st) {
        int srow = wv * 32 + st * 16 + rr;
        a1n[st] = *(const f16x8*)(q1b + (size_t)srow * DD + k0 + quad * 8);
        a2n[st] = *(const f16x8*)(q2b + (size_t)srow * DD + k0 + quad * 8);
      }
    }
#pragma unroll
    for (int jt = 0; jt < 4; ++jt) {
      int brow = jt * 16 + rr;
      f16x8 b1 = *(const f16x8*)&m1_s[cur][brow * LSTR + quad * 8];
      f16x8 b2 = *(const f16x8*)&m2_s[cur][brow * LSTR + quad * 8];
#pragma unroll
      for (int st = 0; st < 2; ++st) {
        acc[st][jt] = __builtin_amdgcn_mfma_f32_16x16x32_f16(a1c[st], b2, acc[st][jt], 0, 0, 0);
        acc[st][jt] = __builtin_amdgcn_mfma_f32_16x16x32_f16(a2c[st], b1, acc[st][jt], 0, 0, 0);
        acc[st][jt] = __builtin_amdgcn_mfma_f32_16x16x32_f16(a1c[st], b1, acc[st][jt], 0, 0, 0);
      }
    }
    if (ks < 15) {
      const int nxt = cur ^ 1;
      split_store4(mr0, &m1_s[nxt][mrow * LSTR + mk * 4], &m2_s[nxt][mrow * LSTR + mk * 4]);
      split_store4(mr1, &m1_s[nxt][(mrow + 32) * LSTR + mk * 4], &m2_s[nxt][(mrow + 32) * LSTR + mk * 4]);
#pragma unroll
      for (int st = 0; st < 2; ++st) { a1c[st] = a1n[st]; a2c[st] = a2n[st]; }
    }
    __syncthreads();
  }
  const float scl = 0.04419417382415922f;  // 1/sqrt(512)
  float* C = sc_out + (size_t)b * SS * MM;
#pragma unroll
  for (int st = 0; st < 2; ++st)
#pragma unroll
    for (int jt = 0; jt < 4; ++jt)
#pragma unroll
      for (int reg = 0; reg < 4; ++reg) {
        int srow = wv * 32 + st * 16 + quad * 4 + reg;
        int scol = j0 + jt * 16 + rr;
        C[(size_t)srow * MM + scol] = acc[st][jt][reg] * scl;
      }
}

// ---------------------------------------------------------------------------
// Kernel 3: per (b,s) row select — REGISTER-RESIDENT. Each thread owns 16
// values (4 float4 chunks) in VGPRs; radix passes are pure VALU (no LDS
// rescans). Survivor probs go to a 128-entry LDS list for the gather.
// XCD-pinned (b = blockIdx&7).
// ---------------------------------------------------------------------------
__device__ __forceinline__ unsigned fkey(float f) {
  unsigned u = __float_as_uint(f);
  return (u & 0x80000000u) ? ~u : (u | 0x80000000u);
}
__device__ __forceinline__ float finv(unsigned u) {
  unsigned b = (u & 0x80000000u) ? (u & 0x7fffffffu) : ~u;
  return __uint_as_float(b);
}

#define NKEPT 128  // top-k=64 + tie margin (ties need bit-equal fp32)

__global__ __launch_bounds__(256) void select_kernel(
    const float* __restrict__ scores, const int* __restrict__ vmask,
    const int* __restrict__ widx, const int* __restrict__ topk,
    const float* __restrict__ memory, float* __restrict__ retrieved,
    float* __restrict__ attn) {
  __shared__ unsigned histw[4 * 256];  // per-wave hist (pass 0); hist0 reused later
  __shared__ int kept_m[NKEPT];
  __shared__ float kept_p[NKEPT];
  __shared__ float red4[4];
  __shared__ unsigned sh_pref;
  __shared__ int sh_k, sh_nkept;
  __shared__ float sh_zinv;

  const int tid = threadIdx.x;
  const int b = blockIdx.x & 7, s = blockIdx.x >> 3;  // XCD-pinned batch
  const int lane = tid & 63, wv = tid >> 6;
  int wi = widx[b] % MM; if (wi < 0) wi += MM;
  const float4* srow4 = (const float4*)(scores + ((size_t)b * SS + s) * MM);
  const int4* vrow4 = (const int4*)(vmask + (size_t)b * MM);
  unsigned* hw = histw + wv * 256;

  if (tid == 0) { sh_pref = 0u; sh_nkept = 0; sh_k = topk[0]; }
  for (int i = tid; i < 1024; i += 256) histw[i] = 0u;
  __syncthreads();

  // load + mask into registers; fkeys; pass-0 histogram; row max
  float4 v[4];
  uint4 u[4];
  float lmax = -INFINITY;
#pragma unroll
  for (int j = 0; j < 4; ++j) {
    int m4 = tid + 256 * j;
    float4 x = srow4[m4];
    int4 mk = vrow4[m4];
    int mb = m4 * 4;
    if (!(mk.x || mb + 0 == wi)) x.x = -INFINITY;
    if (!(mk.y || mb + 1 == wi)) x.y = -INFINITY;
    if (!(mk.z || mb + 2 == wi)) x.z = -INFINITY;
    if (!(mk.w || mb + 3 == wi)) x.w = -INFINITY;
    v[j] = x;
    u[j].x = fkey(x.x); u[j].y = fkey(x.y);
    u[j].z = fkey(x.z); u[j].w = fkey(x.w);
    lmax = fmaxf(lmax, fmaxf(fmaxf(x.x, x.y), fmaxf(x.z, x.w)));
    atomicAdd(&hw[u[j].x >> 24], 1u);
    atomicAdd(&hw[u[j].y >> 24], 1u);
    atomicAdd(&hw[u[j].z >> 24], 1u);
    atomicAdd(&hw[u[j].w >> 24], 1u);
  }
#pragma unroll
  for (int off = 32; off > 0; off >>= 1)
    lmax = fmaxf(lmax, __shfl_xor(lmax, off));
  if (lane == 0) red4[wv] = lmax;
  __syncthreads();
  const float maxv = fmaxf(fmaxf(red4[0], red4[1]), fmaxf(red4[2], red4[3]));

  // radix select (4 passes). Pass 0 uses the 4-way per-wave hist already
  // built; passes 1-3 use a single 256-bin hist (matches are rare).
  for (int pass = 0; pass < 4; ++pass) {
    const int shift = 24 - pass * 8;
    if (pass > 0) {
      const unsigned pref = sh_pref;
      const unsigned hmask = 0xFFFFFFFFu << (shift + 8);
      histw[tid] = 0u;
      __syncthreads();
#pragma unroll
      for (int j = 0; j < 4; ++j) {
        if ((u[j].x & hmask) == pref) atomicAdd(&histw[(u[j].x >> shift) & 0xFFu], 1u);
        if ((u[j].y & hmask) == pref) atomicAdd(&histw[(u[j].y >> shift) & 0xFFu], 1u);
        if ((u[j].z & hmask) == pref) atomicAdd(&histw[(u[j].z >> shift) & 0xFFu], 1u);
        if ((u[j].w & hmask) == pref) atomicAdd(&histw[(u[j].w >> shift) & 0xFFu], 1u);
      }
      __syncthreads();
    }
    if (tid < 64) {
      const int l = tid;
      unsigned h0, h1, h2, h3;
      if (pass == 0) {
        h0 = histw[l * 4 + 0] + histw[256 + l * 4 + 0] + histw[512 + l * 4 + 0] + histw[768 + l * 4 + 0];
        h1 = histw[l * 4 + 1] + histw[256 + l * 4 + 1] + histw[512 + l * 4 + 1] + histw[768 + l * 4 + 1];
        h2 = histw[l * 4 + 2] + histw[256 + l * 4 + 2] + histw[512 + l * 4 + 2] + histw[768 + l * 4 + 2];
        h3 = histw[l * 4 + 3] + histw[256 + l * 4 + 3] + histw[512 + l * 4 + 3] + histw[768 + l * 4 + 3];
      } else {
        h0 = histw[l * 4 + 0]; h1 = histw[l * 4 + 1];
        h2 = histw[l * 4 + 2]; h3 = histw[l * 4 + 3];
      }
      unsigned lsum = h0 + h1 + h2 + h3;
      unsigned g = lsum;  // inclusive suffix scan across lanes
#pragma unroll
      for (int off = 1; off < 64; off <<= 1) {
        unsigned t = __shfl_down(g, off, 64);
        if (l + off < 64) g += t;
      }
      unsigned above = g - lsum;
      unsigned suf3 = h3 + above;
      unsigned suf2 = h2 + suf3;
      unsigned suf1 = h1 + suf2;
      unsigned suf0 = h0 + suf1;
      const unsigned kk = (unsigned)sh_k;
      const unsigned prefc = sh_pref;
      unsigned ge, geN;
      ge = suf0; geN = suf1;
      if (ge >= kk && geN < kk) { sh_pref = prefc | ((unsigned)(4 * l + 0) << shift); sh_k = (int)(kk - geN); }
      ge = suf1; geN = suf2;
      if (ge >= kk && geN < kk) { sh_pref = prefc | ((unsigned)(4 * l + 1) << shift); sh_k = (int)(kk - geN); }
      ge = suf2; geN = suf3;
      if (ge >= kk && geN < kk) { sh_pref = prefc | ((unsigned)(4 * l + 2) << shift); sh_k = (int)(kk - geN); }
      ge = suf3; geN = above;
      if (ge >= kk && geN < kk) { sh_pref = prefc | ((unsigned)(4 * l + 3) << shift); sh_k = (int)(kk - geN); }
    }
    __syncthreads();
  }
  const float thr = finv(sh_pref);

  // probs in registers + Z (wave-shuffle reduction)
  float4 pr[4];
  float lz = 0.f;
#pragma unroll
  for (int j = 0; j < 4; ++j) {
    float4 x = v[j];
    pr[j].x = (x.x >= thr) ? __expf(x.x - maxv) : 0.f;
    pr[j].y = (x.y >= thr) ? __expf(x.y - maxv) : 0.f;
    pr[j].z = (x.z >= thr) ? __expf(x.z - maxv) : 0.f;
    pr[j].w = (x.w >= thr) ? __expf(x.w - maxv) : 0.f;
    lz += pr[j].x + pr[j].y + pr[j].z + pr[j].w;
  }
#pragma unroll
  for (int off = 32; off > 0; off >>= 1) lz += __shfl_xor(lz, off);
  if (lane == 0) red4[wv] = lz;
  __syncthreads();
  if (tid == 0) sh_zinv = 1.0f / (red4[0] + red4[1] + red4[2] + red4[3]);
  __syncthreads();
  const float zinv = sh_zinv;

  // dense attn write (from registers) + kept list (index + raw prob)
  float4* arow4 = (float4*)(attn + ((size_t)b * SS + s) * MM);
#pragma unroll
  for (int j = 0; j < 4; ++j) {
    int m4 = tid + 256 * j;
    float4 p = pr[j];
    arow4[m4] = make_float4(p.x * zinv, p.y * zinv, p.z * zinv, p.w * zinv);
    int mb = m4 * 4;
    if (p.x > 0.f) { int q = atomicAdd(&sh_nkept, 1); if (q < NKEPT) { kept_m[q] = mb + 0; kept_p[q] = p.x; } }
    if (p.y > 0.f) { int q = atomicAdd(&sh_nkept, 1); if (q < NKEPT) { kept_m[q] = mb + 1; kept_p[q] = p.y; } }
    if (p.z > 0.f) { int q = atomicAdd(&sh_nkept, 1); if (q < NKEPT) { kept_m[q] = mb + 2; kept_p[q] = p.z; } }
    if (p.w > 0.f) { int q = atomicAdd(&sh_nkept, 1); if (q < NKEPT) { kept_m[q] = mb + 3; kept_p[q] = p.w; } }
  }
  __syncthreads();
  const int nk = min(sh_nkept, NKEPT);

  // retrieved[b][s][:] = sum_kept p * memory_row (float2 lanes, unrolled x4)
  float ax = 0.f, ay = 0.f;
  const float* mb_ = memory + (size_t)b * MM * DD;
  int i = 0;
  for (; i + 4 <= nk; i += 4) {
    int m0 = kept_m[i], m1 = kept_m[i + 1], m2 = kept_m[i + 2], m3 = kept_m[i + 3];
    float p0 = kept_p[i], p1 = kept_p[i + 1], p2 = kept_p[i + 2], p3 = kept_p[i + 3];
    float2 v0 = ((const float2*)(mb_ + (size_t)m0 * DD))[tid];
    float2 v1 = ((const float2*)(mb_ + (size_t)m1 * DD))[tid];
    float2 v2 = ((const float2*)(mb_ + (size_t)m2 * DD))[tid];
    float2 v3 = ((const float2*)(mb_ + (size_t)m3 * DD))[tid];
    ax += p0 * v0.x + p1 * v1.x + p2 * v2.x + p3 * v3.x;
    ay += p0 * v0.y + p1 * v1.y + p2 * v2.y + p3 * v3.y;
  }
  for (; i < nk; ++i) {
    int m = kept_m[i];
    float p = kept_p[i];
    float2 vv = ((const float2*)(mb_ + (size_t)m * DD))[tid];
    ax += p * vv.x;
    ay += p * vv.y;
  }
  float2* rrow = (float2*)(retrieved + ((size_t)b * SS + s) * DD);
  rrow[tid] = make_float2(ax * zinv, ay * zinv);
}

// ---------------------------------------------------------------------------
extern "C" void kernel_launch(void* const* d_in, const int* in_sizes, int n_in,
                              void* d_out, int out_size, void* d_ws,
                              size_t ws_size, hipStream_t stream) {
  float* memory = (float*)d_in[0];
  const float* usage = (const float*)d_in[1];
  const float* content = (const float*)d_in[2];
  const float* wstr = (const float*)d_in[3];
  const float* query = (const float*)d_in[4];
  const float* W = (const float*)d_in[5];
  const float* ttab = (const float*)d_in[6];
  const float* decay = (const float*)d_in[7];
  const int* vmask = (const int*)d_in[8];
  const int* widx = (const int*)d_in[9];
  const int* topk = (const int*)d_in[10];

  float* out = (float*)d_out;
  float* retrieved = out;                              // B*S*D floats
  float* attn = out + (size_t)BB * SS * DD;            // B*S*M floats
  float* usage_out = attn + (size_t)BB * SS * MM;      // B*M floats

  const size_t qsz = (size_t)BB * SS * DD;             // elems per q array
  float* scores = (float*)d_ws;                        // 16 MB
  f16* q1;
  f16* q2;
  size_t need = (size_t)BB * SS * MM * 4 + 2 * qsz * 2;
  if (ws_size >= need) {
    q1 = (f16*)(scores + (size_t)BB * SS * MM);
    q2 = q1 + qsz;
  } else {
    q2 = (f16*)(attn + (size_t)BB * SS * MM) - qsz;
    q1 = q2 - qsz;
  }

  prep_kernel<<<8 + 512, 256, 0, stream>>>(memory, usage, content, wstr, ttab,
                                           decay, widx, usage_out, query, W,
                                           q1, q2);
  gemm_scores_mfma<<<dim3((MM / 64) * BB), 256, 0, stream>>>(q1, q2, memory,
                                                             scores);
  select_kernel<<<dim3(SS * BB), 256, 0, stream>>>(scores, vmask, widx, topk,
                                                   memory, retrieved, attn);
}